// Round 4
// baseline (848.906 us; speedup 1.0000x reference)
//
#include <hip/hip_runtime.h>
#include <cstddef>
#include <cstdint>

#define NEV   4096
#define NPAIR 32768
#define NEDGE (2*NPAIR)
#define EDIM  768
#define CDIM  256
#define MLPH  1024
#define LLEN  256

typedef unsigned short u16;
typedef __attribute__((ext_vector_type(8))) short bhalf8;
typedef __attribute__((ext_vector_type(4))) float f32x4;

// async global->LDS, 16B per lane (HW: wave-uniform LDS base + lane*16)
#define GLOAD_LDS(g, l) __builtin_amdgcn_global_load_lds( \
    (const __attribute__((address_space(1))) unsigned int*)(g), \
    (__attribute__((address_space(3))) unsigned int*)(l), 16, 0, 0)

__device__ inline u16 f2bf(float f) {
  union { float f; unsigned u; } v; v.f = f;
  unsigned r = v.u + 0x7fffu + ((v.u >> 16) & 1u);
  return (u16)(r >> 16);
}
__device__ inline float bf2f(u16 h) {
  union { unsigned u; float f; } v; v.u = ((unsigned)h) << 16; return v.f;
}

// ---------------------------------------------------------------- utilities
__global__ void k_zero(int* __restrict__ deg, float* __restrict__ out) {
  int i = blockIdx.x * 256 + threadIdx.x;
  if (i < NEV) deg[i] = 0;
  if (i == 0) out[0] = 0.f;
}

// ---------------------------------------------------------------- e_emb: masked span mean, fused bf16 hi/hi/lo split -> Ahat (NEV x 2304)
__global__ void k_embed(const float* __restrict__ sent, const int* __restrict__ es,
                        const int* __restrict__ st, const int* __restrict__ en,
                        u16* __restrict__ Ahat) {
  int node = blockIdx.x;
  int s = es[node];
  int a = st[node];
  int span = en[node] - a;
  float fspan = (float)span;
  const float* base = sent + ((size_t)s * LLEN + a) * EDIM;
  for (int d = threadIdx.x; d < EDIM; d += 256) {
    float acc = 0.f;
    for (int m = 0; m < span; ++m) acc += base[(size_t)m * EDIM + d];
    float e = acc / fspan;
    u16 hi = f2bf(e);
    float lo = e - bf2f(hi);
    size_t b = (size_t)node * (3 * EDIM);
    Ahat[b + d] = hi;
    Ahat[b + EDIM + d] = hi;
    Ahat[b + 2 * EDIM + d] = f2bf(lo);
  }
}

// ---------------------------------------------------------------- CSR build (dst_all = [p1; p0])
__global__ void k_count(const int* __restrict__ pair, int* __restrict__ deg) {
  int e = blockIdx.x * 256 + threadIdx.x;
  if (e >= NEDGE) return;
  int p = (e < NPAIR) ? e : e - NPAIR;
  int dst = (e < NPAIR) ? pair[2 * p + 1] : pair[2 * p];
  atomicAdd(&deg[dst], 1);
}

__global__ void k_scan(const int* __restrict__ deg, int* __restrict__ rowp,
                       int* __restrict__ cursor) {
  __shared__ int part[256];
  int t = threadIdx.x;
  int base = t * 16;
  int sum = 0;
  for (int i = 0; i < 16; ++i) sum += deg[base + i];
  part[t] = sum;
  __syncthreads();
  for (int off = 1; off < 256; off <<= 1) {
    int v = (t >= off) ? part[t - off] : 0;
    __syncthreads();
    part[t] += v;
    __syncthreads();
  }
  int run = (t == 0) ? 0 : part[t - 1];
  for (int i = 0; i < 16; ++i) {
    rowp[base + i] = run;
    cursor[base + i] = 0;
    run += deg[base + i];
  }
  if (t == 255) rowp[NEV] = run;
}

__global__ void k_scatter(const int* __restrict__ pair, const int* __restrict__ rowp,
                          int* __restrict__ cursor, int* __restrict__ e_src,
                          int* __restrict__ e_id) {
  int e = blockIdx.x * 256 + threadIdx.x;
  if (e >= NEDGE) return;
  int p   = (e < NPAIR) ? e : e - NPAIR;
  int src = (e < NPAIR) ? pair[2 * p]     : pair[2 * p + 1];
  int dst = (e < NPAIR) ? pair[2 * p + 1] : pair[2 * p];
  int pos = rowp[dst] + atomicAdd(&cursor[dst], 1);
  e_src[pos] = src;
  e_id[pos]  = e;
}

// ---------------------------------------------------------------- weight conversion: build B^T bf16 [Bh;Bl;Bh] planes, tiled transpose
__global__ __launch_bounds__(256) void cvt_w(const float* __restrict__ W1,
                                             const float* __restrict__ piW,
                                             const float* __restrict__ projW,
                                             u16* __restrict__ BT, int which)
{
  __shared__ float tile[32][33];
  int K = which ? CDIM : EDIM;
  int ld = K * 3;
  int bk = blockIdx.y * 32;
  int bc = blockIdx.x * 32;
  int tx = threadIdx.x & 31, ty = threadIdx.x >> 5;
#pragma unroll
  for (int rr = 0; rr < 4; ++rr) {
    int k = bk + ty + rr * 8;
    int c = bc + tx;
    float v;
    if (which == 0) {
      v = (c < 1024) ? W1[(size_t)k * MLPH + c]
        : (c < 2048) ? W1[(size_t)(EDIM + k) * MLPH + (c - 1024)]
        : piW[(size_t)k * CDIM + (c - 2048)];
    } else {
      v = (c < 1024) ? W1[(size_t)(2 * EDIM + k) * MLPH + c]
        : projW[(size_t)k * CDIM + (c - 1024)];
    }
    tile[ty + rr * 8][tx] = v;
  }
  __syncthreads();
#pragma unroll
  for (int rr = 0; rr < 4; ++rr) {
    int c = bc + ty + rr * 8;
    int k = bk + tx;
    float v = tile[tx][ty + rr * 8];
    u16 hi = f2bf(v);
    float lo = v - bf2f(hi);
    size_t b = (size_t)c * ld;
    BT[b + k] = hi;
    BT[b + K + k] = f2bf(lo);
    BT[b + 2 * K + k] = hi;
  }
}

// ---------------------------------------------------------------- bf16 MFMA GEMM, 128x128 tile, BK=64, 4 waves, 16x16x32 fragments
// Staging via global_load_lds width=16 (linear LDS, lds_byte = c*4096 + tid*16).
__global__ __launch_bounds__(256) void mgemm(
    const u16* __restrict__ A, const u16* __restrict__ BT, int Kp, int mode,
    float* __restrict__ G1, float* __restrict__ G2, u16* __restrict__ Xhat,
    const float* __restrict__ pib, const float* __restrict__ b1,
    const float* __restrict__ pb, float* __restrict__ U, float* __restrict__ V,
    float* __restrict__ h)
{
  __shared__ u16 As[128 * 64];
  __shared__ u16 Bs[128 * 64];
  int tid = threadIdx.x;
  int wave = tid >> 6, lane = tid & 63;
  int bm = blockIdx.y * 128, bn = blockIdx.x * 128;
  int wm = (wave >> 1) * 64, wn = (wave & 1) * 64;

  int srow = tid >> 3;            // 0..31
  int scol = (tid & 7) << 3;      // 0,8,..,56 (bf16 elems)
  const u16* Ag = A + (size_t)(bm + srow) * Kp + scol;
  const u16* Bg = BT + (size_t)(bn + srow) * Kp + scol;
  u16* Asd = &As[tid * 8];        // lds dest: lane-contiguous 16B chunks
  u16* Bsd = &Bs[tid * 8];

  f32x4 acc[4][4];
#pragma unroll
  for (int i = 0; i < 4; ++i)
#pragma unroll
    for (int j = 0; j < 4; ++j) {
      f32x4 z = {0.f, 0.f, 0.f, 0.f};
      acc[i][j] = z;
    }

  int fr = lane & 15;             // fragment row (A) / col (B,D)
  int fq = lane >> 4;             // k-group / D row-group

  for (int k0 = 0; k0 < Kp; k0 += 64) {
#pragma unroll
    for (int c = 0; c < 4; ++c) {
      GLOAD_LDS(Ag + (size_t)(c * 32) * Kp, Asd + c * 2048);
      GLOAD_LDS(Bg + (size_t)(c * 32) * Kp, Bsd + c * 2048);
    }
    __syncthreads();
#pragma unroll
    for (int kk = 0; kk < 2; ++kk) {
      bhalf8 af[4], bf[4];
#pragma unroll
      for (int i = 0; i < 4; ++i)
        af[i] = *(const bhalf8*)&As[(wm + i * 16 + fr) * 64 + kk * 32 + fq * 8];
#pragma unroll
      for (int j = 0; j < 4; ++j)
        bf[j] = *(const bhalf8*)&Bs[(wn + j * 16 + fr) * 64 + kk * 32 + fq * 8];
#pragma unroll
      for (int i = 0; i < 4; ++i)
#pragma unroll
        for (int j = 0; j < 4; ++j)
          acc[i][j] = __builtin_amdgcn_mfma_f32_16x16x32_bf16(af[i], bf[j], acc[i][j], 0, 0, 0);
    }
    __syncthreads();
    Ag += 64;
    Bg += 64;
  }

#pragma unroll
  for (int i = 0; i < 4; ++i) {
    int mrow = bm + wm + i * 16 + fq * 4;
#pragma unroll
    for (int g = 0; g < 4; ++g) {
      int m = mrow + g;
#pragma unroll
      for (int j = 0; j < 4; ++j) {
        int c = bn + wn + j * 16 + fr;
        float vv = acc[i][j][g];
        if (mode == 0) {
          if (c < 1024) {
            G1[(size_t)m * MLPH + c] = vv;
          } else if (c < 2048) {
            G2[(size_t)m * MLPH + (c - 1024)] = vv;
          } else {
            int cc = c - 2048;
            float xv = vv + pib[cc];
            u16 hi = f2bf(xv);
            float lo = xv - bf2f(hi);
            size_t b = (size_t)m * (3 * CDIM);
            Xhat[b + cc] = hi;
            Xhat[b + CDIM + cc] = hi;
            Xhat[b + 2 * CDIM + cc] = f2bf(lo);
          }
        } else {
          if (c < 1024) {
            size_t idx = (size_t)m * MLPH + c;
            U[idx] = G1[idx] + vv + b1[c];
            V[idx] = G2[idx] - vv;
          } else {
            int cc = c - 1024;
            h[(size_t)m * CDIM + cc] = vv + pb[cc];
          }
        }
      }
    }
  }
}

// ---------------------------------------------------------------- per-node attention dots s = h . att
__global__ void k_s(const float* __restrict__ h,
                    const float* __restrict__ asi, const float* __restrict__ adi,
                    const float* __restrict__ asj, const float* __restrict__ adj,
                    float* __restrict__ sv) {
  int node = blockIdx.x * 4 + (threadIdx.x >> 6);
  int lane = threadIdx.x & 63;
  int head = lane >> 4;
  int d0 = (lane & 15) << 2;
  float4 hv = *(const float4*)(h + (size_t)node * CDIM + head * 64 + d0);
  float4 w1 = *(const float4*)(asi + head * 64 + d0);
  float4 w2 = *(const float4*)(adi + head * 64 + d0);
  float4 w3 = *(const float4*)(asj + head * 64 + d0);
  float4 w4 = *(const float4*)(adj + head * 64 + d0);
  float p1 = hv.x * w1.x + hv.y * w1.y + hv.z * w1.z + hv.w * w1.w;
  float p2 = hv.x * w2.x + hv.y * w2.y + hv.z * w2.z + hv.w * w2.w;
  float p3 = hv.x * w3.x + hv.y * w3.y + hv.z * w3.z + hv.w * w3.w;
  float p4 = hv.x * w4.x + hv.y * w4.y + hv.z * w4.z + hv.w * w4.w;
#pragma unroll
  for (int m = 1; m < 16; m <<= 1) {
    p1 += __shfl_xor(p1, m);
    p2 += __shfl_xor(p2, m);
    p3 += __shfl_xor(p3, m);
    p4 += __shfl_xor(p4, m);
  }
  if ((lane & 15) == 0) {
    sv[0 * NEV * 4 + node * 4 + head] = p1;
    sv[1 * NEV * 4 + node * 4 + head] = p2;
    sv[2 * NEV * 4 + node * 4 + head] = p3;
    sv[3 * NEV * 4 + node * 4 + head] = p4;
  }
}

// ---------------------------------------------------------------- pred / softmax / loss / masks (one wave per pair); loss via atomicAdd
__global__ __launch_bounds__(256) void k_pred(
    const float* __restrict__ U, const float* __restrict__ V,
    const int* __restrict__ pair, const float* __restrict__ W2,
    const float* __restrict__ b2, const int* __restrict__ target,
    int* __restrict__ mstate, float* __restrict__ out, float lossCoef)
{
  __shared__ float red[4];
  int wv = threadIdx.x >> 6;
  int p = blockIdx.x * 4 + wv;
  int lane = threadIdx.x & 63;
  int i0 = pair[2 * p], i1 = pair[2 * p + 1];
  const float* u = U + (size_t)i0 * MLPH;
  const float* v = V + (size_t)i1 * MLPH;
  float a0 = 0.f, a1 = 0.f, a2 = 0.f;
  for (int kb = (lane << 2); kb < MLPH; kb += 256) {
    float4 uu = *(const float4*)(u + kb);
    float4 vv = *(const float4*)(v + kb);
    float h0 = fmaxf(uu.x + vv.x, 0.f);
    float h1 = fmaxf(uu.y + vv.y, 0.f);
    float h2 = fmaxf(uu.z + vv.z, 0.f);
    float h3 = fmaxf(uu.w + vv.w, 0.f);
    const float4* w4 = (const float4*)(W2 + 3 * kb);
    float4 wa = w4[0], wb = w4[1], wc = w4[2];
    a0 += h0 * wa.x + h1 * wa.w + h2 * wb.z + h3 * wc.y;
    a1 += h0 * wa.y + h1 * wb.x + h2 * wb.w + h3 * wc.z;
    a2 += h0 * wa.z + h1 * wb.y + h2 * wc.x + h3 * wc.w;
  }
#pragma unroll
  for (int m = 32; m >= 1; m >>= 1) {
    a0 += __shfl_down(a0, m);
    a1 += __shfl_down(a1, m);
    a2 += __shfl_down(a2, m);
  }
  if (lane == 0) {
    a0 += b2[0]; a1 += b2[1]; a2 += b2[2];
    float mx = fmaxf(a0, fmaxf(a1, a2));
    float e0 = expf(a0 - mx), e1 = expf(a1 - mx), e2 = expf(a2 - mx);
    float sum = e0 + e1 + e2;
    int arg = 0; float best = e0;
    if (e1 > best) { best = e1; arg = 1; }
    if (e2 > best) { best = e2; arg = 2; }
    bool conf = (best / sum) > 0.5f;
    mstate[p] = conf ? arg : -1;
    int t = target[p];
    float predt = (t == 0) ? a0 : ((t == 1) ? a1 : a2);
    float logp = (predt - mx) - logf(sum);
    red[wv] = -logp * lossCoef;
    float* po = out + 1 + (size_t)p * 3;
    po[0] = a0; po[1] = a1; po[2] = a2;
  }
  __syncthreads();
  if (threadIdx.x == 0)
    atomicAdd(&out[0], red[0] + red[1] + red[2] + red[3]);
}

// ---------------------------------------------------------------- attention aggregate, one block per dst node; writes Xhat (bf16 hi/hi/lo)
__global__ __launch_bounds__(256) void k_attn(
    const float* __restrict__ h, const float* __restrict__ sv,
    const int* __restrict__ rowp, const int* __restrict__ e_src,
    const int* __restrict__ e_id, const int* __restrict__ mstate,
    const int* __restrict__ rel, u16* __restrict__ Xhat)
{
  int node = blockIdx.x;
  int t = threadIdx.x;          // dim index 0..255 (head = t>>6)
  int head = t >> 6;
  const float* s_si = sv;
  const float* s_di = sv + NEV * 4;
  const float* s_sj = sv + 2 * NEV * 4;
  const float* s_dj = sv + 3 * NEV * 4;
  float sdi = s_di[node * 4 + head];
  float sdj = s_dj[node * 4 + head];
  int beg = rowp[node], end = rowp[node + 1];
  float aself = s_si[node * 4 + head] + sdi;
  aself = aself > 0.f ? aself : 0.2f * aself;
  float mxi = aself;
  float mxj = -1e9f;
  for (int e = beg; e < end; ++e) {
    int eid = e_id[e];
    int pp = (eid < NPAIR) ? eid : eid - NPAIR;
    int st = mstate[pp];
    bool mall = (eid < NPAIR) ? (st == 1) : (st == 2);
    if (!mall) continue;
    int src = e_src[e];
    if (rel[pp] == 0) {
      float a = s_si[src * 4 + head] + sdi;
      a = a > 0.f ? a : 0.2f * a;
      mxi = fmaxf(mxi, a);
    } else {
      float a = s_sj[src * 4 + head] + sdj;
      a = a > 0.f ? a : 0.2f * a;
      mxj = fmaxf(mxj, a);
    }
  }
  float deni = 0.f, denj = 0.f, acci = 0.f, accj = 0.f;
  {
    float ex = expf(aself - mxi);
    deni += ex;
    acci += ex * h[(size_t)node * CDIM + t];
  }
  for (int e = beg; e < end; ++e) {
    int eid = e_id[e];
    int pp = (eid < NPAIR) ? eid : eid - NPAIR;
    int st = mstate[pp];
    bool mall = (eid < NPAIR) ? (st == 1) : (st == 2);
    if (!mall) continue;
    int src = e_src[e];
    float hval = h[(size_t)src * CDIM + t];
    if (rel[pp] == 0) {
      float a = s_si[src * 4 + head] + sdi;
      a = a > 0.f ? a : 0.2f * a;
      float ex = expf(a - mxi);
      deni += ex; acci += ex * hval;
    } else {
      float a = s_sj[src * 4 + head] + sdj;
      a = a > 0.f ? a : 0.2f * a;
      float ex = expf(a - mxj);
      denj += ex; accj += ex * hval;
    }
  }
  float outv = 0.5f * (acci / (deni + 1e-9f)) + 0.5f * (accj / (denj + 1e-9f));
  u16 hi = f2bf(outv);
  float lo = outv - bf2f(hi);
  size_t b = (size_t)node * (3 * CDIM);
  Xhat[b + t] = hi;
  Xhat[b + CDIM + t] = hi;
  Xhat[b + 2 * CDIM + t] = f2bf(lo);
}

// ---------------------------------------------------------------- launch
extern "C" void kernel_launch(void* const* d_in, const int* in_sizes, int n_in,
                              void* d_out, int out_size, void* d_ws, size_t ws_size,
                              hipStream_t stream)
{
  const float* sent      = (const float*)d_in[0];
  const float* proj_in_W = (const float*)d_in[1];
  const float* proj_in_b = (const float*)d_in[2];
  const float* proj_W    = (const float*)d_in[3];
  const float* proj_b    = (const float*)d_in[4];
  const float* asi       = (const float*)d_in[5];
  const float* adi       = (const float*)d_in[6];
  const float* asj       = (const float*)d_in[7];
  const float* adj       = (const float*)d_in[8];
  const float* W1        = (const float*)d_in[9];
  const float* b1        = (const float*)d_in[10];
  const float* W2        = (const float*)d_in[11];
  const float* b2        = (const float*)d_in[12];
  const int*   es        = (const int*)d_in[13];
  const int*   st        = (const int*)d_in[14];
  const int*   en        = (const int*)d_in[15];
  const int*   pair      = (const int*)d_in[16];
  const int*   rel       = (const int*)d_in[17];
  const int*   target    = (const int*)d_in[18];
  float* out = (float*)d_out;

  char* w = (char*)d_ws;
  auto alloc = [&](size_t bytes) -> char* {
    char* p = w;
    w += (bytes + 255) & ~(size_t)255;
    return p;
  };
  u16*   Ahat = (u16*)alloc(sizeof(u16) * (size_t)NEV * 3 * EDIM);
  u16*   BTe  = (u16*)alloc(sizeof(u16) * (size_t)2304 * 2304);
  u16*   BTu  = (u16*)alloc(sizeof(u16) * (size_t)1280 * 768);
  u16*   Xhat = (u16*)alloc(sizeof(u16) * (size_t)NEV * 3 * CDIM);
  float* G1   = (float*)alloc(sizeof(float) * (size_t)NEV * MLPH);
  float* G2   = (float*)alloc(sizeof(float) * (size_t)NEV * MLPH);
  float* U    = (float*)alloc(sizeof(float) * (size_t)NEV * MLPH);
  float* V    = (float*)alloc(sizeof(float) * (size_t)NEV * MLPH);
  float* h    = (float*)alloc(sizeof(float) * (size_t)NEV * CDIM);
  float* sv   = (float*)alloc(sizeof(float) * (size_t)NEV * 16);
  int* deg    = (int*)alloc(sizeof(int) * NEV);
  int* rowp   = (int*)alloc(sizeof(int) * (NEV + 1));
  int* cursor = (int*)alloc(sizeof(int) * NEV);
  int* e_src  = (int*)alloc(sizeof(int) * NEDGE);
  int* e_id   = (int*)alloc(sizeof(int) * NEDGE);
  int* mstate = (int*)alloc(sizeof(int) * NPAIR);

  k_zero<<<(NEV + 255) / 256, 256, 0, stream>>>(deg, out);
  k_embed<<<NEV, 256, 0, stream>>>(sent, es, st, en, Ahat);
  k_count<<<NEDGE / 256, 256, 0, stream>>>(pair, deg);
  k_scan<<<1, 256, 0, stream>>>(deg, rowp, cursor);
  k_scatter<<<NEDGE / 256, 256, 0, stream>>>(pair, rowp, cursor, e_src, e_id);

  cvt_w<<<dim3(2304 / 32, 768 / 32), 256, 0, stream>>>(W1, proj_in_W, proj_W, BTe, 0);
  cvt_w<<<dim3(1280 / 32, 256 / 32), 256, 0, stream>>>(W1, proj_in_W, proj_W, BTu, 1);

  // [G1 | G2 | x0] = e_emb @ [W1a | W1b | proj_in_W]  (bf16x3 via K'=3K)
  mgemm<<<dim3(2304 / 128, NEV / 128), 256, 0, stream>>>(
      Ahat, BTe, 3 * EDIM, 0, G1, G2, Xhat, proj_in_b,
      nullptr, nullptr, nullptr, nullptr, nullptr);

  for (int it = 0; it < 3; ++it) {
    mgemm<<<dim3(1280 / 128, NEV / 128), 256, 0, stream>>>(
        Xhat, BTu, 3 * CDIM, 1, G1, G2, nullptr, nullptr,
        b1, proj_b, U, V, h);
    k_s<<<NEV / 4, 256, 0, stream>>>(h, asi, adi, asj, adj, sv);
    float coef = 1.0f / ((float)(it + 1) * (float)NPAIR);
    k_pred<<<NPAIR / 4, 256, 0, stream>>>(U, V, pair, W2, b2, target, mstate, out, coef);
    k_attn<<<NEV, 256, 0, stream>>>(h, sv, rowp, e_src, e_id, mstate, rel, Xhat);
  }
  (void)in_sizes; (void)n_in; (void)out_size; (void)ws_size;
}

// Round 5
// 587.421 us; speedup vs baseline: 1.4451x; 1.4451x over previous
//
#include <hip/hip_runtime.h>
#include <cstddef>
#include <cstdint>

#define NEV   4096
#define NPAIR 32768
#define NEDGE (2*NPAIR)
#define EDIM  768
#define CDIM  256
#define MLPH  1024
#define LLEN  256

typedef unsigned short u16;
typedef __attribute__((ext_vector_type(8))) short bhalf8;
typedef __attribute__((ext_vector_type(4))) float f32x4;

// async global->LDS, 16B per lane (HW: wave-uniform LDS base + lane*16)
#define GLOAD_LDS(g, l) __builtin_amdgcn_global_load_lds( \
    (const __attribute__((address_space(1))) unsigned int*)(g), \
    (__attribute__((address_space(3))) unsigned int*)(l), 16, 0, 0)

__device__ inline u16 f2bf(float f) {
  union { float f; unsigned u; } v; v.f = f;
  unsigned r = v.u + 0x7fffu + ((v.u >> 16) & 1u);
  return (u16)(r >> 16);
}
__device__ inline float bf2f(u16 h) {
  union { unsigned u; float f; } v; v.u = ((unsigned)h) << 16; return v.f;
}

// ---------------------------------------------------------------- utilities
__global__ void k_zero(int* __restrict__ deg, float* __restrict__ out) {
  int i = blockIdx.x * 256 + threadIdx.x;
  if (i < NEV) deg[i] = 0;
  if (i == 0) out[0] = 0.f;
}

// ---------------------------------------------------------------- e_emb: masked span mean, fused bf16 hi/hi/lo split -> Ahat (NEV x 2304)
__global__ void k_embed(const float* __restrict__ sent, const int* __restrict__ es,
                        const int* __restrict__ st, const int* __restrict__ en,
                        u16* __restrict__ Ahat) {
  int node = blockIdx.x;
  int s = es[node];
  int a = st[node];
  int span = en[node] - a;
  float fspan = (float)span;
  const float* base = sent + ((size_t)s * LLEN + a) * EDIM;
  for (int d = threadIdx.x; d < EDIM; d += 256) {
    float acc = 0.f;
    for (int m = 0; m < span; ++m) acc += base[(size_t)m * EDIM + d];
    float e = acc / fspan;
    u16 hi = f2bf(e);
    float lo = e - bf2f(hi);
    size_t b = (size_t)node * (3 * EDIM);
    Ahat[b + d] = hi;
    Ahat[b + EDIM + d] = hi;
    Ahat[b + 2 * EDIM + d] = f2bf(lo);
  }
}

// ---------------------------------------------------------------- CSR build (dst_all = [p1; p0])
__global__ void k_count(const int* __restrict__ pair, int* __restrict__ deg) {
  int e = blockIdx.x * 256 + threadIdx.x;
  if (e >= NEDGE) return;
  int p = (e < NPAIR) ? e : e - NPAIR;
  int dst = (e < NPAIR) ? pair[2 * p + 1] : pair[2 * p];
  atomicAdd(&deg[dst], 1);
}

__global__ void k_scan(const int* __restrict__ deg, int* __restrict__ rowp,
                       int* __restrict__ cursor) {
  __shared__ int part[256];
  int t = threadIdx.x;
  int base = t * 16;
  int sum = 0;
  for (int i = 0; i < 16; ++i) sum += deg[base + i];
  part[t] = sum;
  __syncthreads();
  for (int off = 1; off < 256; off <<= 1) {
    int v = (t >= off) ? part[t - off] : 0;
    __syncthreads();
    part[t] += v;
    __syncthreads();
  }
  int run = (t == 0) ? 0 : part[t - 1];
  for (int i = 0; i < 16; ++i) {
    rowp[base + i] = run;
    cursor[base + i] = 0;
    run += deg[base + i];
  }
  if (t == 255) rowp[NEV] = run;
}

__global__ void k_scatter(const int* __restrict__ pair, const int* __restrict__ rowp,
                          int* __restrict__ cursor, int* __restrict__ e_src,
                          int* __restrict__ e_id) {
  int e = blockIdx.x * 256 + threadIdx.x;
  if (e >= NEDGE) return;
  int p   = (e < NPAIR) ? e : e - NPAIR;
  int src = (e < NPAIR) ? pair[2 * p]     : pair[2 * p + 1];
  int dst = (e < NPAIR) ? pair[2 * p + 1] : pair[2 * p];
  int pos = rowp[dst] + atomicAdd(&cursor[dst], 1);
  e_src[pos] = src;
  e_id[pos]  = e;
}

// ---------------------------------------------------------------- weight conversion: build B^T bf16 [Bh;Bl;Bh] planes, tiled transpose
__global__ __launch_bounds__(256) void cvt_w(const float* __restrict__ W1,
                                             const float* __restrict__ piW,
                                             const float* __restrict__ projW,
                                             u16* __restrict__ BT, int which)
{
  __shared__ float tile[32][33];
  int K = which ? CDIM : EDIM;
  int ld = K * 3;
  int bk = blockIdx.y * 32;
  int bc = blockIdx.x * 32;
  int tx = threadIdx.x & 31, ty = threadIdx.x >> 5;
#pragma unroll
  for (int rr = 0; rr < 4; ++rr) {
    int k = bk + ty + rr * 8;
    int c = bc + tx;
    float v;
    if (which == 0) {
      v = (c < 1024) ? W1[(size_t)k * MLPH + c]
        : (c < 2048) ? W1[(size_t)(EDIM + k) * MLPH + (c - 1024)]
        : piW[(size_t)k * CDIM + (c - 2048)];
    } else {
      v = (c < 1024) ? W1[(size_t)(2 * EDIM + k) * MLPH + c]
        : projW[(size_t)k * CDIM + (c - 1024)];
    }
    tile[ty + rr * 8][tx] = v;
  }
  __syncthreads();
#pragma unroll
  for (int rr = 0; rr < 4; ++rr) {
    int c = bc + ty + rr * 8;
    int k = bk + tx;
    float v = tile[tx][ty + rr * 8];
    u16 hi = f2bf(v);
    float lo = v - bf2f(hi);
    size_t b = (size_t)c * ld;
    BT[b + k] = hi;
    BT[b + K + k] = f2bf(lo);
    BT[b + 2 * K + k] = hi;
  }
}

// ---------------------------------------------------------------- bf16 MFMA GEMM, 64x128 tile, BK=64, 4 waves (2x2), 16x16x32 frags
// A: M x Kp row-major bf16 ([Ah|Ah|Al]); BT: N x Kp row-major bf16 (B^T, [Bh;Bl;Bh])
// Grid: (N/128, M/64). Staging via global_load_lds width=16 (linear LDS).
__global__ __launch_bounds__(256) void mgemm(
    const u16* __restrict__ A, const u16* __restrict__ BT, int Kp, int mode,
    float* __restrict__ G1, float* __restrict__ G2, u16* __restrict__ Xhat,
    const float* __restrict__ pib, const float* __restrict__ b1,
    const float* __restrict__ pb, float* __restrict__ U, float* __restrict__ V,
    float* __restrict__ h)
{
  __shared__ u16 As[64 * 64];    //  8 KB
  __shared__ u16 Bs[128 * 64];   // 16 KB
  int tid = threadIdx.x;
  int wave = tid >> 6, lane = tid & 63;
  int bm = blockIdx.y * 64, bn = blockIdx.x * 128;
  int wm = (wave >> 1) * 32, wn = (wave & 1) * 64;

  int srow = tid >> 3;            // 0..31
  int scol = (tid & 7) << 3;      // 0,8,..,56 (bf16 elems)
  const u16* Ag = A + (size_t)(bm + srow) * Kp + scol;
  const u16* Bg = BT + (size_t)(bn + srow) * Kp + scol;
  u16* Asd = &As[tid * 8];        // lds dest: lane-contiguous 16B chunks
  u16* Bsd = &Bs[tid * 8];

  f32x4 acc[2][4];
#pragma unroll
  for (int i = 0; i < 2; ++i)
#pragma unroll
    for (int j = 0; j < 4; ++j) {
      f32x4 z = {0.f, 0.f, 0.f, 0.f};
      acc[i][j] = z;
    }

  int fr = lane & 15;             // fragment row (A) / col (B,D)
  int fq = lane >> 4;             // k-group / D row-group

  for (int k0 = 0; k0 < Kp; k0 += 64) {
#pragma unroll
    for (int c = 0; c < 2; ++c)
      GLOAD_LDS(Ag + (size_t)(c * 32) * Kp, Asd + c * 2048);
#pragma unroll
    for (int c = 0; c < 4; ++c)
      GLOAD_LDS(Bg + (size_t)(c * 32) * Kp, Bsd + c * 2048);
    __syncthreads();
#pragma unroll
    for (int kk = 0; kk < 2; ++kk) {
      bhalf8 af[2], bf[4];
#pragma unroll
      for (int i = 0; i < 2; ++i)
        af[i] = *(const bhalf8*)&As[(wm + i * 16 + fr) * 64 + kk * 32 + fq * 8];
#pragma unroll
      for (int j = 0; j < 4; ++j)
        bf[j] = *(const bhalf8*)&Bs[(wn + j * 16 + fr) * 64 + kk * 32 + fq * 8];
#pragma unroll
      for (int i = 0; i < 2; ++i)
#pragma unroll
        for (int j = 0; j < 4; ++j)
          acc[i][j] = __builtin_amdgcn_mfma_f32_16x16x32_bf16(af[i], bf[j], acc[i][j], 0, 0, 0);
    }
    __syncthreads();
    Ag += 64;
    Bg += 64;
  }

#pragma unroll
  for (int i = 0; i < 2; ++i) {
    int mrow = bm + wm + i * 16 + fq * 4;
#pragma unroll
    for (int g = 0; g < 4; ++g) {
      int m = mrow + g;
#pragma unroll
      for (int j = 0; j < 4; ++j) {
        int c = bn + wn + j * 16 + fr;
        float vv = acc[i][j][g];
        if (mode == 0) {
          if (c < 1024) {
            G1[(size_t)m * MLPH + c] = vv;
          } else if (c < 2048) {
            G2[(size_t)m * MLPH + (c - 1024)] = vv;
          } else {
            int cc = c - 2048;
            float xv = vv + pib[cc];
            u16 hi = f2bf(xv);
            float lo = xv - bf2f(hi);
            size_t b = (size_t)m * (3 * CDIM);
            Xhat[b + cc] = hi;
            Xhat[b + CDIM + cc] = hi;
            Xhat[b + 2 * CDIM + cc] = f2bf(lo);
          }
        } else {
          if (c < 1024) {
            size_t idx = (size_t)m * MLPH + c;
            U[idx] = G1[idx] + vv + b1[c];
            V[idx] = G2[idx] - vv;
          } else {
            int cc = c - 1024;
            h[(size_t)m * CDIM + cc] = vv + pb[cc];
          }
        }
      }
    }
  }
}

// ---------------------------------------------------------------- per-node attention dots s = h . att
__global__ void k_s(const float* __restrict__ h,
                    const float* __restrict__ asi, const float* __restrict__ adi,
                    const float* __restrict__ asj, const float* __restrict__ adj,
                    float* __restrict__ sv) {
  int node = blockIdx.x * 4 + (threadIdx.x >> 6);
  int lane = threadIdx.x & 63;
  int head = lane >> 4;
  int d0 = (lane & 15) << 2;
  float4 hv = *(const float4*)(h + (size_t)node * CDIM + head * 64 + d0);
  float4 w1 = *(const float4*)(asi + head * 64 + d0);
  float4 w2 = *(const float4*)(adi + head * 64 + d0);
  float4 w3 = *(const float4*)(asj + head * 64 + d0);
  float4 w4 = *(const float4*)(adj + head * 64 + d0);
  float p1 = hv.x * w1.x + hv.y * w1.y + hv.z * w1.z + hv.w * w1.w;
  float p2 = hv.x * w2.x + hv.y * w2.y + hv.z * w2.z + hv.w * w2.w;
  float p3 = hv.x * w3.x + hv.y * w3.y + hv.z * w3.z + hv.w * w3.w;
  float p4 = hv.x * w4.x + hv.y * w4.y + hv.z * w4.z + hv.w * w4.w;
#pragma unroll
  for (int m = 1; m < 16; m <<= 1) {
    p1 += __shfl_xor(p1, m);
    p2 += __shfl_xor(p2, m);
    p3 += __shfl_xor(p3, m);
    p4 += __shfl_xor(p4, m);
  }
  if ((lane & 15) == 0) {
    sv[0 * NEV * 4 + node * 4 + head] = p1;
    sv[1 * NEV * 4 + node * 4 + head] = p2;
    sv[2 * NEV * 4 + node * 4 + head] = p3;
    sv[3 * NEV * 4 + node * 4 + head] = p4;
  }
}

// ---------------------------------------------------------------- pred / softmax / loss / masks (one wave per pair)
__global__ __launch_bounds__(256) void k_pred(
    const float* __restrict__ U, const float* __restrict__ V,
    const int* __restrict__ pair, const float* __restrict__ W2,
    const float* __restrict__ b2, const int* __restrict__ target,
    int* __restrict__ mstate, float* __restrict__ out,
    float* __restrict__ partials, float lossCoef)
{
  __shared__ float red[4];
  int wv = threadIdx.x >> 6;
  int p = blockIdx.x * 4 + wv;
  int lane = threadIdx.x & 63;
  int i0 = pair[2 * p], i1 = pair[2 * p + 1];
  const float* u = U + (size_t)i0 * MLPH;
  const float* v = V + (size_t)i1 * MLPH;
  float a0 = 0.f, a1 = 0.f, a2 = 0.f;
  for (int kb = (lane << 2); kb < MLPH; kb += 256) {
    float4 uu = *(const float4*)(u + kb);
    float4 vv = *(const float4*)(v + kb);
    float h0 = fmaxf(uu.x + vv.x, 0.f);
    float h1 = fmaxf(uu.y + vv.y, 0.f);
    float h2 = fmaxf(uu.z + vv.z, 0.f);
    float h3 = fmaxf(uu.w + vv.w, 0.f);
    const float4* w4 = (const float4*)(W2 + 3 * kb);
    float4 wa = w4[0], wb = w4[1], wc = w4[2];
    a0 += h0 * wa.x + h1 * wa.w + h2 * wb.z + h3 * wc.y;
    a1 += h0 * wa.y + h1 * wb.x + h2 * wb.w + h3 * wc.z;
    a2 += h0 * wa.z + h1 * wb.y + h2 * wc.x + h3 * wc.w;
  }
#pragma unroll
  for (int m = 32; m >= 1; m >>= 1) {
    a0 += __shfl_down(a0, m);
    a1 += __shfl_down(a1, m);
    a2 += __shfl_down(a2, m);
  }
  if (lane == 0) {
    a0 += b2[0]; a1 += b2[1]; a2 += b2[2];
    float mx = fmaxf(a0, fmaxf(a1, a2));
    float e0 = expf(a0 - mx), e1 = expf(a1 - mx), e2 = expf(a2 - mx);
    float sum = e0 + e1 + e2;
    int arg = 0; float best = e0;
    if (e1 > best) { best = e1; arg = 1; }
    if (e2 > best) { best = e2; arg = 2; }
    bool conf = (best / sum) > 0.5f;
    mstate[p] = conf ? arg : -1;
    int t = target[p];
    float predt = (t == 0) ? a0 : ((t == 1) ? a1 : a2);
    float logp = (predt - mx) - logf(sum);
    red[wv] = -logp * lossCoef;
    float* po = out + 1 + (size_t)p * 3;
    po[0] = a0; po[1] = a1; po[2] = a2;
  }
  __syncthreads();
  if (threadIdx.x == 0) partials[blockIdx.x] = red[0] + red[1] + red[2] + red[3];
}

__global__ void k_lossred(const float* __restrict__ partials, float* __restrict__ out, int n) {
  __shared__ float sm[256];
  float s = 0.f;
  for (int i = threadIdx.x; i < n; i += 256) s += partials[i];
  sm[threadIdx.x] = s;
  __syncthreads();
  for (int off = 128; off; off >>= 1) {
    if (threadIdx.x < off) sm[threadIdx.x] += sm[threadIdx.x + off];
    __syncthreads();
  }
  if (threadIdx.x == 0) out[0] += sm[0];
}

// ---------------------------------------------------------------- attention aggregate, one block per dst node; writes Xhat (bf16 hi/hi/lo)
__global__ __launch_bounds__(256) void k_attn(
    const float* __restrict__ h, const float* __restrict__ sv,
    const int* __restrict__ rowp, const int* __restrict__ e_src,
    const int* __restrict__ e_id, const int* __restrict__ mstate,
    const int* __restrict__ rel, u16* __restrict__ Xhat)
{
  int node = blockIdx.x;
  int t = threadIdx.x;          // dim index 0..255 (head = t>>6)
  int head = t >> 6;
  const float* s_si = sv;
  const float* s_di = sv + NEV * 4;
  const float* s_sj = sv + 2 * NEV * 4;
  const float* s_dj = sv + 3 * NEV * 4;
  float sdi = s_di[node * 4 + head];
  float sdj = s_dj[node * 4 + head];
  int beg = rowp[node], end = rowp[node + 1];
  float aself = s_si[node * 4 + head] + sdi;
  aself = aself > 0.f ? aself : 0.2f * aself;
  float mxi = aself;
  float mxj = -1e9f;
  for (int e = beg; e < end; ++e) {
    int eid = e_id[e];
    int pp = (eid < NPAIR) ? eid : eid - NPAIR;
    int st = mstate[pp];
    bool mall = (eid < NPAIR) ? (st == 1) : (st == 2);
    if (!mall) continue;
    int src = e_src[e];
    if (rel[pp] == 0) {
      float a = s_si[src * 4 + head] + sdi;
      a = a > 0.f ? a : 0.2f * a;
      mxi = fmaxf(mxi, a);
    } else {
      float a = s_sj[src * 4 + head] + sdj;
      a = a > 0.f ? a : 0.2f * a;
      mxj = fmaxf(mxj, a);
    }
  }
  float deni = 0.f, denj = 0.f, acci = 0.f, accj = 0.f;
  {
    float ex = expf(aself - mxi);
    deni += ex;
    acci += ex * h[(size_t)node * CDIM + t];
  }
  for (int e = beg; e < end; ++e) {
    int eid = e_id[e];
    int pp = (eid < NPAIR) ? eid : eid - NPAIR;
    int st = mstate[pp];
    bool mall = (eid < NPAIR) ? (st == 1) : (st == 2);
    if (!mall) continue;
    int src = e_src[e];
    float hval = h[(size_t)src * CDIM + t];
    if (rel[pp] == 0) {
      float a = s_si[src * 4 + head] + sdi;
      a = a > 0.f ? a : 0.2f * a;
      float ex = expf(a - mxi);
      deni += ex; acci += ex * hval;
    } else {
      float a = s_sj[src * 4 + head] + sdj;
      a = a > 0.f ? a : 0.2f * a;
      float ex = expf(a - mxj);
      denj += ex; accj += ex * hval;
    }
  }
  float outv = 0.5f * (acci / (deni + 1e-9f)) + 0.5f * (accj / (denj + 1e-9f));
  u16 hi = f2bf(outv);
  float lo = outv - bf2f(hi);
  size_t b = (size_t)node * (3 * CDIM);
  Xhat[b + t] = hi;
  Xhat[b + CDIM + t] = hi;
  Xhat[b + 2 * CDIM + t] = f2bf(lo);
}

// ---------------------------------------------------------------- launch
extern "C" void kernel_launch(void* const* d_in, const int* in_sizes, int n_in,
                              void* d_out, int out_size, void* d_ws, size_t ws_size,
                              hipStream_t stream)
{
  const float* sent      = (const float*)d_in[0];
  const float* proj_in_W = (const float*)d_in[1];
  const float* proj_in_b = (const float*)d_in[2];
  const float* proj_W    = (const float*)d_in[3];
  const float* proj_b    = (const float*)d_in[4];
  const float* asi       = (const float*)d_in[5];
  const float* adi       = (const float*)d_in[6];
  const float* asj       = (const float*)d_in[7];
  const float* adj       = (const float*)d_in[8];
  const float* W1        = (const float*)d_in[9];
  const float* b1        = (const float*)d_in[10];
  const float* W2        = (const float*)d_in[11];
  const float* b2        = (const float*)d_in[12];
  const int*   es        = (const int*)d_in[13];
  const int*   st        = (const int*)d_in[14];
  const int*   en        = (const int*)d_in[15];
  const int*   pair      = (const int*)d_in[16];
  const int*   rel       = (const int*)d_in[17];
  const int*   target    = (const int*)d_in[18];
  float* out = (float*)d_out;

  char* w = (char*)d_ws;
  auto alloc = [&](size_t bytes) -> char* {
    char* p = w;
    w += (bytes + 255) & ~(size_t)255;
    return p;
  };
  u16*   Ahat = (u16*)alloc(sizeof(u16) * (size_t)NEV * 3 * EDIM);
  u16*   BTe  = (u16*)alloc(sizeof(u16) * (size_t)2304 * 2304);
  u16*   BTu  = (u16*)alloc(sizeof(u16) * (size_t)1280 * 768);
  u16*   Xhat = (u16*)alloc(sizeof(u16) * (size_t)NEV * 3 * CDIM);
  float* G1   = (float*)alloc(sizeof(float) * (size_t)NEV * MLPH);
  float* G2   = (float*)alloc(sizeof(float) * (size_t)NEV * MLPH);
  float* U    = (float*)alloc(sizeof(float) * (size_t)NEV * MLPH);
  float* V    = (float*)alloc(sizeof(float) * (size_t)NEV * MLPH);
  float* h    = (float*)alloc(sizeof(float) * (size_t)NEV * CDIM);
  float* sv   = (float*)alloc(sizeof(float) * (size_t)NEV * 16);
  float* lpart= (float*)alloc(sizeof(float) * (NPAIR / 4));
  int* deg    = (int*)alloc(sizeof(int) * NEV);
  int* rowp   = (int*)alloc(sizeof(int) * (NEV + 1));
  int* cursor = (int*)alloc(sizeof(int) * NEV);
  int* e_src  = (int*)alloc(sizeof(int) * NEDGE);
  int* e_id   = (int*)alloc(sizeof(int) * NEDGE);
  int* mstate = (int*)alloc(sizeof(int) * NPAIR);

  k_zero<<<(NEV + 255) / 256, 256, 0, stream>>>(deg, out);
  k_embed<<<NEV, 256, 0, stream>>>(sent, es, st, en, Ahat);
  k_count<<<NEDGE / 256, 256, 0, stream>>>(pair, deg);
  k_scan<<<1, 256, 0, stream>>>(deg, rowp, cursor);
  k_scatter<<<NEDGE / 256, 256, 0, stream>>>(pair, rowp, cursor, e_src, e_id);

  cvt_w<<<dim3(2304 / 32, 768 / 32), 256, 0, stream>>>(W1, proj_in_W, proj_W, BTe, 0);
  cvt_w<<<dim3(1280 / 32, 256 / 32), 256, 0, stream>>>(W1, proj_in_W, proj_W, BTu, 1);

  // [G1 | G2 | x0] = e_emb @ [W1a | W1b | proj_in_W]  (bf16x3 via K'=3K)
  mgemm<<<dim3(2304 / 128, NEV / 64), 256, 0, stream>>>(
      Ahat, BTe, 3 * EDIM, 0, G1, G2, Xhat, proj_in_b,
      nullptr, nullptr, nullptr, nullptr, nullptr);

  for (int it = 0; it < 3; ++it) {
    mgemm<<<dim3(1280 / 128, NEV / 64), 256, 0, stream>>>(
        Xhat, BTu, 3 * CDIM, 1, G1, G2, nullptr, nullptr,
        b1, proj_b, U, V, h);
    k_s<<<NEV / 4, 256, 0, stream>>>(h, asi, adi, asj, adj, sv);
    float coef = 1.0f / ((float)(it + 1) * (float)NPAIR);
    k_pred<<<NPAIR / 4, 256, 0, stream>>>(U, V, pair, W2, b2, target, mstate, out, lpart, coef);
    k_lossred<<<1, 256, 0, stream>>>(lpart, out, NPAIR / 4);
    k_attn<<<NEV, 256, 0, stream>>>(h, sv, rowp, e_src, e_id, mstate, rel, Xhat);
  }
  (void)in_sizes; (void)n_in; (void)out_size; (void)ws_size;
}

// Round 6
// 574.647 us; speedup vs baseline: 1.4773x; 1.0222x over previous
//
#include <hip/hip_runtime.h>
#include <cstddef>
#include <cstdint>

#define NEV   4096
#define NPAIR 32768
#define NEDGE (2*NPAIR)
#define EDIM  768
#define CDIM  256
#define MLPH  1024
#define LLEN  256

typedef unsigned short u16;
typedef __attribute__((ext_vector_type(8))) short bhalf8;
typedef __attribute__((ext_vector_type(4))) float f32x4;

// async global->LDS, 16B per lane (HW: wave-uniform LDS base + lane*16)
#define GLOAD_LDS(g, l) __builtin_amdgcn_global_load_lds( \
    (const __attribute__((address_space(1))) unsigned int*)(g), \
    (__attribute__((address_space(3))) unsigned int*)(l), 16, 0, 0)

__device__ inline u16 f2bf(float f) {
  union { float f; unsigned u; } v; v.f = f;
  unsigned r = v.u + 0x7fffu + ((v.u >> 16) & 1u);
  return (u16)(r >> 16);
}
__device__ inline float bf2f(u16 h) {
  union { unsigned u; float f; } v; v.u = ((unsigned)h) << 16; return v.f;
}

// ---------------------------------------------------------------- utilities
__global__ void k_zero(int* __restrict__ deg, int* __restrict__ pdeg,
                       float* __restrict__ out) {
  int i = blockIdx.x * 256 + threadIdx.x;
  if (i < NEV) { deg[i] = 0; pdeg[i] = 0; }
  if (i == 0) out[0] = 0.f;
}

// ---------------------------------------------------------------- e_emb: masked span mean, fused bf16 hi/hi/lo split -> Ahat (NEV x 2304)
__global__ void k_embed(const float* __restrict__ sent, const int* __restrict__ es,
                        const int* __restrict__ st, const int* __restrict__ en,
                        u16* __restrict__ Ahat) {
  int node = blockIdx.x;
  int s = es[node];
  int a = st[node];
  int span = en[node] - a;
  float fspan = (float)span;
  const float* base = sent + ((size_t)s * LLEN + a) * EDIM;
  for (int d = threadIdx.x; d < EDIM; d += 256) {
    float acc = 0.f;
    for (int m = 0; m < span; ++m) acc += base[(size_t)m * EDIM + d];
    float e = acc / fspan;
    u16 hi = f2bf(e);
    float lo = e - bf2f(hi);
    size_t b = (size_t)node * (3 * EDIM);
    Ahat[b + d] = hi;
    Ahat[b + EDIM + d] = hi;
    Ahat[b + 2 * EDIM + d] = f2bf(lo);
  }
}

// ---------------------------------------------------------------- CSR build (edges, dst_all = [p1; p0])
__global__ void k_count(const int* __restrict__ pair, int* __restrict__ deg) {
  int e = blockIdx.x * 256 + threadIdx.x;
  if (e >= NEDGE) return;
  int p = (e < NPAIR) ? e : e - NPAIR;
  int dst = (e < NPAIR) ? pair[2 * p + 1] : pair[2 * p];
  atomicAdd(&deg[dst], 1);
}

__global__ void k_scan(const int* __restrict__ deg, int* __restrict__ rowp,
                       int* __restrict__ cursor) {
  __shared__ int part[256];
  int t = threadIdx.x;
  int base = t * 16;
  int sum = 0;
  for (int i = 0; i < 16; ++i) sum += deg[base + i];
  part[t] = sum;
  __syncthreads();
  for (int off = 1; off < 256; off <<= 1) {
    int v = (t >= off) ? part[t - off] : 0;
    __syncthreads();
    part[t] += v;
    __syncthreads();
  }
  int run = (t == 0) ? 0 : part[t - 1];
  for (int i = 0; i < 16; ++i) {
    rowp[base + i] = run;
    cursor[base + i] = 0;
    run += deg[base + i];
  }
  if (t == 255) rowp[NEV] = run;
}

__global__ void k_scatter(const int* __restrict__ pair, const int* __restrict__ rowp,
                          int* __restrict__ cursor, int* __restrict__ e_src,
                          int* __restrict__ e_id) {
  int e = blockIdx.x * 256 + threadIdx.x;
  if (e >= NEDGE) return;
  int p   = (e < NPAIR) ? e : e - NPAIR;
  int src = (e < NPAIR) ? pair[2 * p]     : pair[2 * p + 1];
  int dst = (e < NPAIR) ? pair[2 * p + 1] : pair[2 * p];
  int pos = rowp[dst] + atomicAdd(&cursor[dst], 1);
  e_src[pos] = src;
  e_id[pos]  = e;
}

// ---------------------------------------------------------------- pair-CSR keyed by p0 (for k_pred U-row reuse)
__global__ void k_pcount(const int* __restrict__ pair, int* __restrict__ pdeg) {
  int p = blockIdx.x * 256 + threadIdx.x;
  if (p >= NPAIR) return;
  atomicAdd(&pdeg[pair[2 * p]], 1);
}

__global__ void k_pscatter(const int* __restrict__ pair, const int* __restrict__ prow,
                           int* __restrict__ pcur, int* __restrict__ pidx) {
  int p = blockIdx.x * 256 + threadIdx.x;
  if (p >= NPAIR) return;
  int pos = prow[pair[2 * p]] + atomicAdd(&pcur[pair[2 * p]], 1);
  pidx[pos] = p;
}

// ---------------------------------------------------------------- weight conversion: build B^T bf16 [Bh;Bl;Bh] planes, tiled transpose
__global__ __launch_bounds__(256) void cvt_w(const float* __restrict__ W1,
                                             const float* __restrict__ piW,
                                             const float* __restrict__ projW,
                                             u16* __restrict__ BT, int which)
{
  __shared__ float tile[32][33];
  int K = which ? CDIM : EDIM;
  int ld = K * 3;
  int bk = blockIdx.y * 32;
  int bc = blockIdx.x * 32;
  int tx = threadIdx.x & 31, ty = threadIdx.x >> 5;
#pragma unroll
  for (int rr = 0; rr < 4; ++rr) {
    int k = bk + ty + rr * 8;
    int c = bc + tx;
    float v;
    if (which == 0) {
      v = (c < 1024) ? W1[(size_t)k * MLPH + c]
        : (c < 2048) ? W1[(size_t)(EDIM + k) * MLPH + (c - 1024)]
        : piW[(size_t)k * CDIM + (c - 2048)];
    } else {
      v = (c < 1024) ? W1[(size_t)(2 * EDIM + k) * MLPH + c]
        : projW[(size_t)k * CDIM + (c - 1024)];
    }
    tile[ty + rr * 8][tx] = v;
  }
  __syncthreads();
#pragma unroll
  for (int rr = 0; rr < 4; ++rr) {
    int c = bc + ty + rr * 8;
    int k = bk + tx;
    float v = tile[tx][ty + rr * 8];
    u16 hi = f2bf(v);
    float lo = v - bf2f(hi);
    size_t b = (size_t)c * ld;
    BT[b + k] = hi;
    BT[b + K + k] = f2bf(lo);
    BT[b + 2 * K + k] = hi;
  }
}

// ---------------------------------------------------------------- bf16 MFMA GEMM, 64x64 tile, BK=64, 4 waves (2x2 of 32x32), XCD swizzle
// A: M x Kp row-major bf16 ([Ah|Ah|Al]); BT: N x Kp row-major bf16 (B^T, [Bh;Bl;Bh])
// Grid: (N/64, M/64), nwg % 8 == 0 required (XCD chunk swizzle).
__global__ __launch_bounds__(256) void mgemm(
    const u16* __restrict__ A, const u16* __restrict__ BT, int Kp, int mode,
    float* __restrict__ G1, float* __restrict__ G2, u16* __restrict__ Xhat,
    const float* __restrict__ pib, const float* __restrict__ b1,
    const float* __restrict__ pb, float* __restrict__ U, float* __restrict__ V,
    float* __restrict__ h)
{
  __shared__ u16 As[64 * 64];    // 8 KB
  __shared__ u16 Bs[64 * 64];    // 8 KB
  int tid = threadIdx.x;
  int wave = tid >> 6, lane = tid & 63;

  // XCD-chunked bijective swizzle: each XCD owns contiguous 1/8 of grid
  int gx = gridDim.x;
  int nwg = gx * gridDim.y;
  int orig = blockIdx.y * gx + blockIdx.x;
  int swz = (orig & 7) * (nwg >> 3) + (orig >> 3);
  int bm = (swz / gx) * 64, bn = (swz % gx) * 64;

  int wm = (wave >> 1) * 32, wn = (wave & 1) * 32;

  int srow = tid >> 3;            // 0..31
  int scol = (tid & 7) << 3;      // 0,8,..,56 (bf16 elems)
  const u16* Ag = A + (size_t)(bm + srow) * Kp + scol;
  const u16* Bg = BT + (size_t)(bn + srow) * Kp + scol;
  u16* Asd = &As[tid * 8];        // lds dest: lane-contiguous 16B chunks
  u16* Bsd = &Bs[tid * 8];

  f32x4 acc[2][2];
#pragma unroll
  for (int i = 0; i < 2; ++i)
#pragma unroll
    for (int j = 0; j < 2; ++j) {
      f32x4 z = {0.f, 0.f, 0.f, 0.f};
      acc[i][j] = z;
    }

  int fr = lane & 15;             // fragment row (A) / col (B,D)
  int fq = lane >> 4;             // k-group / D row-group

  for (int k0 = 0; k0 < Kp; k0 += 64) {
#pragma unroll
    for (int c = 0; c < 2; ++c) {
      GLOAD_LDS(Ag + (size_t)(c * 32) * Kp, Asd + c * 2048);
      GLOAD_LDS(Bg + (size_t)(c * 32) * Kp, Bsd + c * 2048);
    }
    __syncthreads();
#pragma unroll
    for (int kk = 0; kk < 2; ++kk) {
      bhalf8 af[2], bf[2];
#pragma unroll
      for (int i = 0; i < 2; ++i)
        af[i] = *(const bhalf8*)&As[(wm + i * 16 + fr) * 64 + kk * 32 + fq * 8];
#pragma unroll
      for (int j = 0; j < 2; ++j)
        bf[j] = *(const bhalf8*)&Bs[(wn + j * 16 + fr) * 64 + kk * 32 + fq * 8];
#pragma unroll
      for (int i = 0; i < 2; ++i)
#pragma unroll
        for (int j = 0; j < 2; ++j)
          acc[i][j] = __builtin_amdgcn_mfma_f32_16x16x32_bf16(af[i], bf[j], acc[i][j], 0, 0, 0);
    }
    __syncthreads();
    Ag += 64;
    Bg += 64;
  }

#pragma unroll
  for (int i = 0; i < 2; ++i) {
    int mrow = bm + wm + i * 16 + fq * 4;
#pragma unroll
    for (int g = 0; g < 4; ++g) {
      int m = mrow + g;
#pragma unroll
      for (int j = 0; j < 2; ++j) {
        int c = bn + wn + j * 16 + fr;
        float vv = acc[i][j][g];
        if (mode == 0) {
          if (c < 1024) {
            G1[(size_t)m * MLPH + c] = vv;
          } else if (c < 2048) {
            G2[(size_t)m * MLPH + (c - 1024)] = vv;
          } else {
            int cc = c - 2048;
            float xv = vv + pib[cc];
            u16 hi = f2bf(xv);
            float lo = xv - bf2f(hi);
            size_t b = (size_t)m * (3 * CDIM);
            Xhat[b + cc] = hi;
            Xhat[b + CDIM + cc] = hi;
            Xhat[b + 2 * CDIM + cc] = f2bf(lo);
          }
        } else {
          if (c < 1024) {
            size_t idx = (size_t)m * MLPH + c;
            U[idx] = G1[idx] + vv + b1[c];
            V[idx] = G2[idx] - vv;
          } else {
            int cc = c - 1024;
            h[(size_t)m * CDIM + cc] = vv + pb[cc];
          }
        }
      }
    }
  }
}

// ---------------------------------------------------------------- per-node attention dots s = h . att
__global__ void k_s(const float* __restrict__ h,
                    const float* __restrict__ asi, const float* __restrict__ adi,
                    const float* __restrict__ asj, const float* __restrict__ adj,
                    float* __restrict__ sv) {
  int node = blockIdx.x * 4 + (threadIdx.x >> 6);
  int lane = threadIdx.x & 63;
  int head = lane >> 4;
  int d0 = (lane & 15) << 2;
  float4 hv = *(const float4*)(h + (size_t)node * CDIM + head * 64 + d0);
  float4 w1 = *(const float4*)(asi + head * 64 + d0);
  float4 w2 = *(const float4*)(adi + head * 64 + d0);
  float4 w3 = *(const float4*)(asj + head * 64 + d0);
  float4 w4 = *(const float4*)(adj + head * 64 + d0);
  float p1 = hv.x * w1.x + hv.y * w1.y + hv.z * w1.z + hv.w * w1.w;
  float p2 = hv.x * w2.x + hv.y * w2.y + hv.z * w2.z + hv.w * w2.w;
  float p3 = hv.x * w3.x + hv.y * w3.y + hv.z * w3.z + hv.w * w3.w;
  float p4 = hv.x * w4.x + hv.y * w4.y + hv.z * w4.z + hv.w * w4.w;
#pragma unroll
  for (int m = 1; m < 16; m <<= 1) {
    p1 += __shfl_xor(p1, m);
    p2 += __shfl_xor(p2, m);
    p3 += __shfl_xor(p3, m);
    p4 += __shfl_xor(p4, m);
  }
  if ((lane & 15) == 0) {
    sv[0 * NEV * 4 + node * 4 + head] = p1;
    sv[1 * NEV * 4 + node * 4 + head] = p2;
    sv[2 * NEV * 4 + node * 4 + head] = p3;
    sv[3 * NEV * 4 + node * 4 + head] = p4;
  }
}

// ---------------------------------------------------------------- pred, p0-grouped: one block per node, U row in LDS, 4 waves over pairs
__global__ __launch_bounds__(256) void k_pred_g(
    const float* __restrict__ U, const float* __restrict__ V,
    const int* __restrict__ pair, const int* __restrict__ prow,
    const int* __restrict__ pidx, const float* __restrict__ W2,
    const float* __restrict__ b2, const int* __restrict__ target,
    int* __restrict__ mstate, float* __restrict__ out,
    float* __restrict__ partials, float lossCoef)
{
  __shared__ float ush[MLPH];
  __shared__ float red[4];
  int n = blockIdx.x;
  int tid = threadIdx.x;
  const float* u = U + (size_t)n * MLPH;
#pragma unroll
  for (int i = 0; i < 4; ++i) ush[tid + i * 256] = u[tid + i * 256];
  __syncthreads();
  int wv = tid >> 6, lane = tid & 63;
  int beg = prow[n], end = prow[n + 1];
  float lsum = 0.f;
  for (int ip = beg + wv; ip < end; ip += 4) {
    int p = pidx[ip];
    int i1 = pair[2 * p + 1];
    const float* v = V + (size_t)i1 * MLPH;
    float a0 = 0.f, a1 = 0.f, a2 = 0.f;
    for (int kb = (lane << 2); kb < MLPH; kb += 256) {
      float4 uu = *(const float4*)(&ush[kb]);
      float4 vv = *(const float4*)(v + kb);
      float h0 = fmaxf(uu.x + vv.x, 0.f);
      float h1 = fmaxf(uu.y + vv.y, 0.f);
      float h2 = fmaxf(uu.z + vv.z, 0.f);
      float h3 = fmaxf(uu.w + vv.w, 0.f);
      const float4* w4 = (const float4*)(W2 + 3 * kb);
      float4 wa = w4[0], wb = w4[1], wc = w4[2];
      a0 += h0 * wa.x + h1 * wa.w + h2 * wb.z + h3 * wc.y;
      a1 += h0 * wa.y + h1 * wb.x + h2 * wb.w + h3 * wc.z;
      a2 += h0 * wa.z + h1 * wb.y + h2 * wc.x + h3 * wc.w;
    }
#pragma unroll
    for (int m = 32; m >= 1; m >>= 1) {
      a0 += __shfl_down(a0, m);
      a1 += __shfl_down(a1, m);
      a2 += __shfl_down(a2, m);
    }
    if (lane == 0) {
      a0 += b2[0]; a1 += b2[1]; a2 += b2[2];
      float mx = fmaxf(a0, fmaxf(a1, a2));
      float e0 = expf(a0 - mx), e1 = expf(a1 - mx), e2 = expf(a2 - mx);
      float sum = e0 + e1 + e2;
      int arg = 0; float best = e0;
      if (e1 > best) { best = e1; arg = 1; }
      if (e2 > best) { best = e2; arg = 2; }
      bool conf = (best / sum) > 0.5f;
      mstate[p] = conf ? arg : -1;
      int t = target[p];
      float predt = (t == 0) ? a0 : ((t == 1) ? a1 : a2);
      float logp = (predt - mx) - logf(sum);
      lsum += -logp * lossCoef;
      float* po = out + 1 + (size_t)p * 3;
      po[0] = a0; po[1] = a1; po[2] = a2;
    }
  }
  if (lane == 0) red[wv] = lsum;
  __syncthreads();
  if (tid == 0) partials[n] = red[0] + red[1] + red[2] + red[3];
}

__global__ void k_lossred(const float* __restrict__ partials, float* __restrict__ out, int n) {
  __shared__ float sm[256];
  float s = 0.f;
  for (int i = threadIdx.x; i < n; i += 256) s += partials[i];
  sm[threadIdx.x] = s;
  __syncthreads();
  for (int off = 128; off; off >>= 1) {
    if (threadIdx.x < off) sm[threadIdx.x] += sm[threadIdx.x + off];
    __syncthreads();
  }
  if (threadIdx.x == 0) out[0] += sm[0];
}

// ---------------------------------------------------------------- attention aggregate, one block per dst node; writes Xhat (bf16 hi/hi/lo)
__global__ __launch_bounds__(256) void k_attn(
    const float* __restrict__ h, const float* __restrict__ sv,
    const int* __restrict__ rowp, const int* __restrict__ e_src,
    const int* __restrict__ e_id, const int* __restrict__ mstate,
    const int* __restrict__ rel, u16* __restrict__ Xhat)
{
  int node = blockIdx.x;
  int t = threadIdx.x;          // dim index 0..255 (head = t>>6)
  int head = t >> 6;
  const float* s_si = sv;
  const float* s_di = sv + NEV * 4;
  const float* s_sj = sv + 2 * NEV * 4;
  const float* s_dj = sv + 3 * NEV * 4;
  float sdi = s_di[node * 4 + head];
  float sdj = s_dj[node * 4 + head];
  int beg = rowp[node], end = rowp[node + 1];
  float aself = s_si[node * 4 + head] + sdi;
  aself = aself > 0.f ? aself : 0.2f * aself;
  float mxi = aself;
  float mxj = -1e9f;
  for (int e = beg; e < end; ++e) {
    int eid = e_id[e];
    int pp = (eid < NPAIR) ? eid : eid - NPAIR;
    int st = mstate[pp];
    bool mall = (eid < NPAIR) ? (st == 1) : (st == 2);
    if (!mall) continue;
    int src = e_src[e];
    if (rel[pp] == 0) {
      float a = s_si[src * 4 + head] + sdi;
      a = a > 0.f ? a : 0.2f * a;
      mxi = fmaxf(mxi, a);
    } else {
      float a = s_sj[src * 4 + head] + sdj;
      a = a > 0.f ? a : 0.2f * a;
      mxj = fmaxf(mxj, a);
    }
  }
  float deni = 0.f, denj = 0.f, acci = 0.f, accj = 0.f;
  {
    float ex = expf(aself - mxi);
    deni += ex;
    acci += ex * h[(size_t)node * CDIM + t];
  }
  for (int e = beg; e < end; ++e) {
    int eid = e_id[e];
    int pp = (eid < NPAIR) ? eid : eid - NPAIR;
    int st = mstate[pp];
    bool mall = (eid < NPAIR) ? (st == 1) : (st == 2);
    if (!mall) continue;
    int src = e_src[e];
    float hval = h[(size_t)src * CDIM + t];
    if (rel[pp] == 0) {
      float a = s_si[src * 4 + head] + sdi;
      a = a > 0.f ? a : 0.2f * a;
      float ex = expf(a - mxi);
      deni += ex; acci += ex * hval;
    } else {
      float a = s_sj[src * 4 + head] + sdj;
      a = a > 0.f ? a : 0.2f * a;
      float ex = expf(a - mxj);
      denj += ex; accj += ex * hval;
    }
  }
  float outv = 0.5f * (acci / (deni + 1e-9f)) + 0.5f * (accj / (denj + 1e-9f));
  u16 hi = f2bf(outv);
  float lo = outv - bf2f(hi);
  size_t b = (size_t)node * (3 * CDIM);
  Xhat[b + t] = hi;
  Xhat[b + CDIM + t] = hi;
  Xhat[b + 2 * CDIM + t] = f2bf(lo);
}

// ---------------------------------------------------------------- launch
extern "C" void kernel_launch(void* const* d_in, const int* in_sizes, int n_in,
                              void* d_out, int out_size, void* d_ws, size_t ws_size,
                              hipStream_t stream)
{
  const float* sent      = (const float*)d_in[0];
  const float* proj_in_W = (const float*)d_in[1];
  const float* proj_in_b = (const float*)d_in[2];
  const float* proj_W    = (const float*)d_in[3];
  const float* proj_b    = (const float*)d_in[4];
  const float* asi       = (const float*)d_in[5];
  const float* adi       = (const float*)d_in[6];
  const float* asj       = (const float*)d_in[7];
  const float* adj       = (const float*)d_in[8];
  const float* W1        = (const float*)d_in[9];
  const float* b1        = (const float*)d_in[10];
  const float* W2        = (const float*)d_in[11];
  const float* b2        = (const float*)d_in[12];
  const int*   es        = (const int*)d_in[13];
  const int*   st        = (const int*)d_in[14];
  const int*   en        = (const int*)d_in[15];
  const int*   pair      = (const int*)d_in[16];
  const int*   rel       = (const int*)d_in[17];
  const int*   target    = (const int*)d_in[18];
  float* out = (float*)d_out;

  char* w = (char*)d_ws;
  auto alloc = [&](size_t bytes) -> char* {
    char* p = w;
    w += (bytes + 255) & ~(size_t)255;
    return p;
  };
  u16*   Ahat = (u16*)alloc(sizeof(u16) * (size_t)NEV * 3 * EDIM);
  u16*   BTe  = (u16*)alloc(sizeof(u16) * (size_t)2304 * 2304);
  u16*   BTu  = (u16*)alloc(sizeof(u16) * (size_t)1280 * 768);
  u16*   Xhat = (u16*)alloc(sizeof(u16) * (size_t)NEV * 3 * CDIM);
  float* G1   = (float*)alloc(sizeof(float) * (size_t)NEV * MLPH);
  float* G2   = (float*)alloc(sizeof(float) * (size_t)NEV * MLPH);
  float* U    = (float*)alloc(sizeof(float) * (size_t)NEV * MLPH);
  float* V    = (float*)alloc(sizeof(float) * (size_t)NEV * MLPH);
  float* h    = (float*)alloc(sizeof(float) * (size_t)NEV * CDIM);
  float* sv   = (float*)alloc(sizeof(float) * (size_t)NEV * 16);
  float* lpart= (float*)alloc(sizeof(float) * NEV);
  int* deg    = (int*)alloc(sizeof(int) * NEV);
  int* rowp   = (int*)alloc(sizeof(int) * (NEV + 1));
  int* cursor = (int*)alloc(sizeof(int) * NEV);
  int* e_src  = (int*)alloc(sizeof(int) * NEDGE);
  int* e_id   = (int*)alloc(sizeof(int) * NEDGE);
  int* pdeg   = (int*)alloc(sizeof(int) * NEV);
  int* prow   = (int*)alloc(sizeof(int) * (NEV + 1));
  int* pcur   = (int*)alloc(sizeof(int) * NEV);
  int* pidx   = (int*)alloc(sizeof(int) * NPAIR);
  int* mstate = (int*)alloc(sizeof(int) * NPAIR);

  k_zero<<<(NEV + 255) / 256, 256, 0, stream>>>(deg, pdeg, out);
  k_embed<<<NEV, 256, 0, stream>>>(sent, es, st, en, Ahat);
  k_count<<<NEDGE / 256, 256, 0, stream>>>(pair, deg);
  k_scan<<<1, 256, 0, stream>>>(deg, rowp, cursor);
  k_scatter<<<NEDGE / 256, 256, 0, stream>>>(pair, rowp, cursor, e_src, e_id);
  k_pcount<<<NPAIR / 256, 256, 0, stream>>>(pair, pdeg);
  k_scan<<<1, 256, 0, stream>>>(pdeg, prow, pcur);
  k_pscatter<<<NPAIR / 256, 256, 0, stream>>>(pair, prow, pcur, pidx);

  cvt_w<<<dim3(2304 / 32, 768 / 32), 256, 0, stream>>>(W1, proj_in_W, proj_W, BTe, 0);
  cvt_w<<<dim3(1280 / 32, 256 / 32), 256, 0, stream>>>(W1, proj_in_W, proj_W, BTu, 1);

  // [G1 | G2 | x0] = e_emb @ [W1a | W1b | proj_in_W]  (bf16x3 via K'=3K)
  mgemm<<<dim3(2304 / 64, NEV / 64), 256, 0, stream>>>(
      Ahat, BTe, 3 * EDIM, 0, G1, G2, Xhat, proj_in_b,
      nullptr, nullptr, nullptr, nullptr, nullptr);

  for (int it = 0; it < 3; ++it) {
    mgemm<<<dim3(1280 / 64, NEV / 64), 256, 0, stream>>>(
        Xhat, BTu, 3 * CDIM, 1, G1, G2, nullptr, nullptr,
        b1, proj_b, U, V, h);
    k_s<<<NEV / 4, 256, 0, stream>>>(h, asi, adi, asj, adj, sv);
    float coef = 1.0f / ((float)(it + 1) * (float)NPAIR);
    k_pred_g<<<NEV, 256, 0, stream>>>(U, V, pair, prow, pidx, W2, b2, target,
                                      mstate, out, lpart, coef);
    k_lossred<<<1, 256, 0, stream>>>(lpart, out, NEV);
    k_attn<<<NEV, 256, 0, stream>>>(h, sv, rowp, e_src, e_id, mstate, rel, Xhat);
  }
  (void)in_sizes; (void)n_in; (void)out_size; (void)ws_size;
}

// Round 7
// 544.267 us; speedup vs baseline: 1.5597x; 1.0558x over previous
//
#include <hip/hip_runtime.h>
#include <cstddef>
#include <cstdint>

#define NEV   4096
#define NPAIR 32768
#define NEDGE (2*NPAIR)
#define EDIM  768
#define CDIM  256
#define MLPH  1024
#define LLEN  256

typedef unsigned short u16;
typedef __attribute__((ext_vector_type(8))) short bhalf8;
typedef __attribute__((ext_vector_type(4))) float f32x4;

// async global->LDS, 16B per lane (HW: wave-uniform LDS base + lane*16)
#define GLOAD_LDS(g, l) __builtin_amdgcn_global_load_lds( \
    (const __attribute__((address_space(1))) unsigned int*)(g), \
    (__attribute__((address_space(3))) unsigned int*)(l), 16, 0, 0)

__device__ inline u16 f2bf(float f) {
  union { float f; unsigned u; } v; v.f = f;
  unsigned r = v.u + 0x7fffu + ((v.u >> 16) & 1u);
  return (u16)(r >> 16);
}
__device__ inline float bf2f(u16 h) {
  union { unsigned u; float f; } v; v.u = ((unsigned)h) << 16; return v.f;
}

// ---------------------------------------------------------------- utilities
__global__ void k_zero(int* __restrict__ deg, int* __restrict__ pdeg,
                       float* __restrict__ out) {
  int i = blockIdx.x * 256 + threadIdx.x;
  if (i < NEV) { deg[i] = 0; pdeg[i] = 0; }
  if (i == 0) out[0] = 0.f;
}

// ---------------------------------------------------------------- e_emb: masked span mean, fused bf16 hi/hi/lo split -> Ahat (NEV x 2304)
__global__ void k_embed(const float* __restrict__ sent, const int* __restrict__ es,
                        const int* __restrict__ st, const int* __restrict__ en,
                        u16* __restrict__ Ahat) {
  int node = blockIdx.x;
  int s = es[node];
  int a = st[node];
  int span = en[node] - a;
  float fspan = (float)span;
  const float* base = sent + ((size_t)s * LLEN + a) * EDIM;
  for (int d = threadIdx.x; d < EDIM; d += 256) {
    float acc = 0.f;
    for (int m = 0; m < span; ++m) acc += base[(size_t)m * EDIM + d];
    float e = acc / fspan;
    u16 hi = f2bf(e);
    float lo = e - bf2f(hi);
    size_t b = (size_t)node * (3 * EDIM);
    Ahat[b + d] = hi;
    Ahat[b + EDIM + d] = hi;
    Ahat[b + 2 * EDIM + d] = f2bf(lo);
  }
}

// ---------------------------------------------------------------- fused CSR builds (edge-CSR by dst, pair-CSR by p0)
__global__ void k_countF(const int* __restrict__ pair, int* __restrict__ deg,
                         int* __restrict__ pdeg) {
  int e = blockIdx.x * 256 + threadIdx.x;
  if (e >= NEDGE) return;
  int p = (e < NPAIR) ? e : e - NPAIR;
  int dst = (e < NPAIR) ? pair[2 * p + 1] : pair[2 * p];
  atomicAdd(&deg[dst], 1);
  if (e < NPAIR) atomicAdd(&pdeg[pair[2 * e]], 1);
}

__device__ inline void scan_body(const int* __restrict__ deg, int* __restrict__ rowp,
                                 int* __restrict__ cursor, int* part) {
  int t = threadIdx.x;
  int base = t * 16;
  int sum = 0;
  for (int i = 0; i < 16; ++i) sum += deg[base + i];
  part[t] = sum;
  __syncthreads();
  for (int off = 1; off < 256; off <<= 1) {
    int v = (t >= off) ? part[t - off] : 0;
    __syncthreads();
    part[t] += v;
    __syncthreads();
  }
  int run = (t == 0) ? 0 : part[t - 1];
  for (int i = 0; i < 16; ++i) {
    rowp[base + i] = run;
    cursor[base + i] = 0;
    run += deg[base + i];
  }
  if (t == 255) rowp[NEV] = run;
}

__global__ void k_scanF(const int* __restrict__ deg, int* __restrict__ rowp,
                        int* __restrict__ cursor, const int* __restrict__ pdeg,
                        int* __restrict__ prow, int* __restrict__ pcur) {
  __shared__ int part[256];
  scan_body(deg, rowp, cursor, part);
  __syncthreads();
  scan_body(pdeg, prow, pcur, part);
}

__global__ void k_scatterF(const int* __restrict__ pair, const int* __restrict__ rowp,
                           int* __restrict__ cursor, int* __restrict__ e_src,
                           int* __restrict__ e_id, const int* __restrict__ prow,
                           int* __restrict__ pcur, int* __restrict__ pidx) {
  int e = blockIdx.x * 256 + threadIdx.x;
  if (e >= NEDGE) return;
  int p   = (e < NPAIR) ? e : e - NPAIR;
  int src = (e < NPAIR) ? pair[2 * p]     : pair[2 * p + 1];
  int dst = (e < NPAIR) ? pair[2 * p + 1] : pair[2 * p];
  int pos = rowp[dst] + atomicAdd(&cursor[dst], 1);
  e_src[pos] = src;
  e_id[pos]  = e;
  if (e < NPAIR) {
    int pp = prow[pair[2 * e]] + atomicAdd(&pcur[pair[2 * e]], 1);
    pidx[pp] = e;
  }
}

// ---------------------------------------------------------------- weight conversion (both targets in one launch)
// blockIdx.y < 24 -> BTe (K=768, N=2304); else BTu (K=256, N=1280)
__global__ __launch_bounds__(256) void cvt_w(const float* __restrict__ W1,
                                             const float* __restrict__ piW,
                                             const float* __restrict__ projW,
                                             u16* __restrict__ BTe,
                                             u16* __restrict__ BTu)
{
  __shared__ float tile[32][33];
  int which = (blockIdx.y >= 24) ? 1 : 0;
  if (which && blockIdx.x >= 40) return;
  u16* BT = which ? BTu : BTe;
  int K = which ? CDIM : EDIM;
  int ld = K * 3;
  int bk = (which ? (blockIdx.y - 24) : blockIdx.y) * 32;
  int bc = blockIdx.x * 32;
  int tx = threadIdx.x & 31, ty = threadIdx.x >> 5;
#pragma unroll
  for (int rr = 0; rr < 4; ++rr) {
    int k = bk + ty + rr * 8;
    int c = bc + tx;
    float v;
    if (which == 0) {
      v = (c < 1024) ? W1[(size_t)k * MLPH + c]
        : (c < 2048) ? W1[(size_t)(EDIM + k) * MLPH + (c - 1024)]
        : piW[(size_t)k * CDIM + (c - 2048)];
    } else {
      v = (c < 1024) ? W1[(size_t)(2 * EDIM + k) * MLPH + c]
        : projW[(size_t)k * CDIM + (c - 1024)];
    }
    tile[ty + rr * 8][tx] = v;
  }
  __syncthreads();
#pragma unroll
  for (int rr = 0; rr < 4; ++rr) {
    int c = bc + ty + rr * 8;
    int k = bk + tx;
    float v = tile[tx][ty + rr * 8];
    u16 hi = f2bf(v);
    float lo = v - bf2f(hi);
    size_t b = (size_t)c * ld;
    BT[b + k] = hi;
    BT[b + K + k] = f2bf(lo);
    BT[b + 2 * K + k] = hi;
  }
}

// ---------------------------------------------------------------- bf16 MFMA GEMM, 64x128 tile, BK=64, 4 waves (2x2), XCD swizzle
// mode 1 additionally computes attention dots sv from h-region tiles (fused k_s).
__global__ __launch_bounds__(256) void mgemm(
    const u16* __restrict__ A, const u16* __restrict__ BT, int Kp, int mode,
    float* __restrict__ G1, float* __restrict__ G2, u16* __restrict__ Xhat,
    const float* __restrict__ pib, const float* __restrict__ b1,
    const float* __restrict__ pb, float* __restrict__ U, float* __restrict__ V,
    float* __restrict__ h, const float* __restrict__ asi,
    const float* __restrict__ adi, const float* __restrict__ asj,
    const float* __restrict__ adj, float* __restrict__ sv)
{
  __shared__ u16 As[64 * 64];    //  8 KB
  __shared__ u16 Bs[128 * 64];   // 16 KB
  int tid = threadIdx.x;
  int wave = tid >> 6, lane = tid & 63;

  // XCD-chunked bijective swizzle (nwg % 8 == 0)
  int gx = gridDim.x;
  int nwg = gx * gridDim.y;
  int orig = blockIdx.y * gx + blockIdx.x;
  int swz = (orig & 7) * (nwg >> 3) + (orig >> 3);
  int bm = (swz / gx) * 64, bn = (swz % gx) * 128;

  int wm = (wave >> 1) * 32, wn = (wave & 1) * 64;

  int srow = tid >> 3;            // 0..31
  int scol = (tid & 7) << 3;      // 0,8,..,56 (bf16 elems)
  const u16* Ag = A + (size_t)(bm + srow) * Kp + scol;
  const u16* Bg = BT + (size_t)(bn + srow) * Kp + scol;
  u16* Asd = &As[tid * 8];
  u16* Bsd = &Bs[tid * 8];

  f32x4 acc[2][4];
#pragma unroll
  for (int i = 0; i < 2; ++i)
#pragma unroll
    for (int j = 0; j < 4; ++j) {
      f32x4 z = {0.f, 0.f, 0.f, 0.f};
      acc[i][j] = z;
    }

  int fr = lane & 15;
  int fq = lane >> 4;

  for (int k0 = 0; k0 < Kp; k0 += 64) {
#pragma unroll
    for (int c = 0; c < 2; ++c)
      GLOAD_LDS(Ag + (size_t)(c * 32) * Kp, Asd + c * 2048);
#pragma unroll
    for (int c = 0; c < 4; ++c)
      GLOAD_LDS(Bg + (size_t)(c * 32) * Kp, Bsd + c * 2048);
    __syncthreads();
#pragma unroll
    for (int kk = 0; kk < 2; ++kk) {
      bhalf8 af[2], bf[4];
#pragma unroll
      for (int i = 0; i < 2; ++i)
        af[i] = *(const bhalf8*)&As[(wm + i * 16 + fr) * 64 + kk * 32 + fq * 8];
#pragma unroll
      for (int j = 0; j < 4; ++j)
        bf[j] = *(const bhalf8*)&Bs[(wn + j * 16 + fr) * 64 + kk * 32 + fq * 8];
#pragma unroll
      for (int i = 0; i < 2; ++i)
#pragma unroll
        for (int j = 0; j < 4; ++j)
          acc[i][j] = __builtin_amdgcn_mfma_f32_16x16x32_bf16(af[i], bf[j], acc[i][j], 0, 0, 0);
    }
    __syncthreads();
    Ag += 64;
    Bg += 64;
  }

#pragma unroll
  for (int i = 0; i < 2; ++i) {
    int mrow = bm + wm + i * 16 + fq * 4;
#pragma unroll
    for (int g = 0; g < 4; ++g) {
      int m = mrow + g;
#pragma unroll
      for (int j = 0; j < 4; ++j) {
        int c = bn + wn + j * 16 + fr;
        float vv = acc[i][j][g];
        if (mode == 0) {
          if (c < 1024) {
            G1[(size_t)m * MLPH + c] = vv;
          } else if (c < 2048) {
            G2[(size_t)m * MLPH + (c - 1024)] = vv;
          } else {
            int cc = c - 2048;
            float xv = vv + pib[cc];
            u16 hi = f2bf(xv);
            float lo = xv - bf2f(hi);
            size_t b = (size_t)m * (3 * CDIM);
            Xhat[b + cc] = hi;
            Xhat[b + CDIM + cc] = hi;
            Xhat[b + 2 * CDIM + cc] = f2bf(lo);
          }
        } else {
          if (c < 1024) {
            size_t idx = (size_t)m * MLPH + c;
            U[idx] = G1[idx] + vv + b1[c];
            V[idx] = G2[idx] - vv;
          } else {
            int cc = c - 1024;
            h[(size_t)m * CDIM + cc] = vv + pb[cc];
          }
        }
      }
    }
  }

  // fused k_s: attention dots from h-region tiles (mode 1, bn >= MLPH)
  if (mode == 1 && bn >= MLPH) {
    int hbase = bn - MLPH + wn;          // 0,64,128,192 (one head per wave)
    int head = hbase >> 6;
#pragma unroll
    for (int i = 0; i < 2; ++i) {
#pragma unroll
      for (int g = 0; g < 4; ++g) {
        int m = bm + wm + i * 16 + fq * 4 + g;
        float p0 = 0.f, p1 = 0.f, p2 = 0.f, p3 = 0.f;
#pragma unroll
        for (int j = 0; j < 4; ++j) {
          int hc = hbase + j * 16 + fr;  // 0..255 (head*64 + d)
          float hv = acc[i][j][g] + pb[hc];
          p0 += hv * asi[hc];
          p1 += hv * adi[hc];
          p2 += hv * asj[hc];
          p3 += hv * adj[hc];
        }
#pragma unroll
        for (int mm = 1; mm < 16; mm <<= 1) {
          p0 += __shfl_xor(p0, mm);
          p1 += __shfl_xor(p1, mm);
          p2 += __shfl_xor(p2, mm);
          p3 += __shfl_xor(p3, mm);
        }
        if (fr == 0) {
          sv[0 * NEV * 4 + m * 4 + head] = p0;
          sv[1 * NEV * 4 + m * 4 + head] = p1;
          sv[2 * NEV * 4 + m * 4 + head] = p2;
          sv[3 * NEV * 4 + m * 4 + head] = p3;
        }
      }
    }
  }
}

// ---------------------------------------------------------------- pred, p0-grouped: one block per node, U row in LDS, 4 waves over pairs
__global__ __launch_bounds__(256) void k_pred_g(
    const float* __restrict__ U, const float* __restrict__ V,
    const int* __restrict__ pair, const int* __restrict__ prow,
    const int* __restrict__ pidx, const float* __restrict__ W2,
    const float* __restrict__ b2, const int* __restrict__ target,
    int* __restrict__ mstate, float* __restrict__ out,
    float* __restrict__ partials, float lossCoef)
{
  __shared__ float ush[MLPH];
  __shared__ float red[4];
  int n = blockIdx.x;
  int tid = threadIdx.x;
  const float* u = U + (size_t)n * MLPH;
#pragma unroll
  for (int i = 0; i < 4; ++i) ush[tid + i * 256] = u[tid + i * 256];
  __syncthreads();
  int wv = tid >> 6, lane = tid & 63;
  int beg = prow[n], end = prow[n + 1];
  float lsum = 0.f;
  for (int ip = beg + wv; ip < end; ip += 4) {
    int p = pidx[ip];
    int i1 = pair[2 * p + 1];
    const float* v = V + (size_t)i1 * MLPH;
    float a0 = 0.f, a1 = 0.f, a2 = 0.f;
    for (int kb = (lane << 2); kb < MLPH; kb += 256) {
      float4 uu = *(const float4*)(&ush[kb]);
      float4 vv = *(const float4*)(v + kb);
      float h0 = fmaxf(uu.x + vv.x, 0.f);
      float h1 = fmaxf(uu.y + vv.y, 0.f);
      float h2 = fmaxf(uu.z + vv.z, 0.f);
      float h3 = fmaxf(uu.w + vv.w, 0.f);
      const float4* w4 = (const float4*)(W2 + 3 * kb);
      float4 wa = w4[0], wb = w4[1], wc = w4[2];
      a0 += h0 * wa.x + h1 * wa.w + h2 * wb.z + h3 * wc.y;
      a1 += h0 * wa.y + h1 * wb.x + h2 * wb.w + h3 * wc.z;
      a2 += h0 * wa.z + h1 * wb.y + h2 * wc.x + h3 * wc.w;
    }
#pragma unroll
    for (int m = 32; m >= 1; m >>= 1) {
      a0 += __shfl_down(a0, m);
      a1 += __shfl_down(a1, m);
      a2 += __shfl_down(a2, m);
    }
    if (lane == 0) {
      a0 += b2[0]; a1 += b2[1]; a2 += b2[2];
      float mx = fmaxf(a0, fmaxf(a1, a2));
      float e0 = expf(a0 - mx), e1 = expf(a1 - mx), e2 = expf(a2 - mx);
      float sum = e0 + e1 + e2;
      int arg = 0; float best = e0;
      if (e1 > best) { best = e1; arg = 1; }
      if (e2 > best) { best = e2; arg = 2; }
      bool conf = (best / sum) > 0.5f;
      mstate[p] = conf ? arg : -1;
      int t = target[p];
      float predt = (t == 0) ? a0 : ((t == 1) ? a1 : a2);
      float logp = (predt - mx) - logf(sum);
      lsum += -logp * lossCoef;
      float* po = out + 1 + (size_t)p * 3;
      po[0] = a0; po[1] = a1; po[2] = a2;
    }
  }
  if (lane == 0) red[wv] = lsum;
  __syncthreads();
  if (tid == 0) partials[n] = red[0] + red[1] + red[2] + red[3];
}

// ---------------------------------------------------------------- attention aggregate (block per dst node) + fused loss reduction (block 0)
__global__ __launch_bounds__(256) void k_attn(
    const float* __restrict__ h, const float* __restrict__ sv,
    const int* __restrict__ rowp, const int* __restrict__ e_src,
    const int* __restrict__ e_id, const int* __restrict__ mstate,
    const int* __restrict__ rel, u16* __restrict__ Xhat,
    const float* __restrict__ lpart, float* __restrict__ out)
{
  int node = blockIdx.x;
  int t = threadIdx.x;          // dim index 0..255 (head = t>>6)
  int head = t >> 6;
  const float* s_si = sv;
  const float* s_di = sv + NEV * 4;
  const float* s_sj = sv + 2 * NEV * 4;
  const float* s_dj = sv + 3 * NEV * 4;
  float sdi = s_di[node * 4 + head];
  float sdj = s_dj[node * 4 + head];
  int beg = rowp[node], end = rowp[node + 1];
  float aself = s_si[node * 4 + head] + sdi;
  aself = aself > 0.f ? aself : 0.2f * aself;
  float mxi = aself;
  float mxj = -1e9f;
  for (int e = beg; e < end; ++e) {
    int eid = e_id[e];
    int pp = (eid < NPAIR) ? eid : eid - NPAIR;
    int st = mstate[pp];
    bool mall = (eid < NPAIR) ? (st == 1) : (st == 2);
    if (!mall) continue;
    int src = e_src[e];
    if (rel[pp] == 0) {
      float a = s_si[src * 4 + head] + sdi;
      a = a > 0.f ? a : 0.2f * a;
      mxi = fmaxf(mxi, a);
    } else {
      float a = s_sj[src * 4 + head] + sdj;
      a = a > 0.f ? a : 0.2f * a;
      mxj = fmaxf(mxj, a);
    }
  }
  float deni = 0.f, denj = 0.f, acci = 0.f, accj = 0.f;
  {
    float ex = expf(aself - mxi);
    deni += ex;
    acci += ex * h[(size_t)node * CDIM + t];
  }
  for (int e = beg; e < end; ++e) {
    int eid = e_id[e];
    int pp = (eid < NPAIR) ? eid : eid - NPAIR;
    int st = mstate[pp];
    bool mall = (eid < NPAIR) ? (st == 1) : (st == 2);
    if (!mall) continue;
    int src = e_src[e];
    float hval = h[(size_t)src * CDIM + t];
    if (rel[pp] == 0) {
      float a = s_si[src * 4 + head] + sdi;
      a = a > 0.f ? a : 0.2f * a;
      float ex = expf(a - mxi);
      deni += ex; acci += ex * hval;
    } else {
      float a = s_sj[src * 4 + head] + sdj;
      a = a > 0.f ? a : 0.2f * a;
      float ex = expf(a - mxj);
      denj += ex; accj += ex * hval;
    }
  }
  float outv = 0.5f * (acci / (deni + 1e-9f)) + 0.5f * (accj / (denj + 1e-9f));
  u16 hi = f2bf(outv);
  float lo = outv - bf2f(hi);
  size_t b = (size_t)node * (3 * CDIM);
  Xhat[b + t] = hi;
  Xhat[b + CDIM + t] = hi;
  Xhat[b + 2 * CDIM + t] = f2bf(lo);

  // fused loss reduction (one block)
  if (blockIdx.x == 0) {
    __shared__ float sm[256];
    float s = 0.f;
    for (int i = t; i < NEV; i += 256) s += lpart[i];
    sm[t] = s;
    __syncthreads();
    for (int off = 128; off; off >>= 1) {
      if (t < off) sm[t] += sm[t + off];
      __syncthreads();
    }
    if (t == 0) out[0] += sm[0];
  }
}

// ---------------------------------------------------------------- launch
extern "C" void kernel_launch(void* const* d_in, const int* in_sizes, int n_in,
                              void* d_out, int out_size, void* d_ws, size_t ws_size,
                              hipStream_t stream)
{
  const float* sent      = (const float*)d_in[0];
  const float* proj_in_W = (const float*)d_in[1];
  const float* proj_in_b = (const float*)d_in[2];
  const float* proj_W    = (const float*)d_in[3];
  const float* proj_b    = (const float*)d_in[4];
  const float* asi       = (const float*)d_in[5];
  const float* adi       = (const float*)d_in[6];
  const float* asj       = (const float*)d_in[7];
  const float* adj       = (const float*)d_in[8];
  const float* W1        = (const float*)d_in[9];
  const float* b1        = (const float*)d_in[10];
  const float* W2        = (const float*)d_in[11];
  const float* b2        = (const float*)d_in[12];
  const int*   es        = (const int*)d_in[13];
  const int*   st        = (const int*)d_in[14];
  const int*   en        = (const int*)d_in[15];
  const int*   pair      = (const int*)d_in[16];
  const int*   rel       = (const int*)d_in[17];
  const int*   target    = (const int*)d_in[18];
  float* out = (float*)d_out;

  char* w = (char*)d_ws;
  auto alloc = [&](size_t bytes) -> char* {
    char* p = w;
    w += (bytes + 255) & ~(size_t)255;
    return p;
  };
  u16*   Ahat = (u16*)alloc(sizeof(u16) * (size_t)NEV * 3 * EDIM);
  u16*   BTe  = (u16*)alloc(sizeof(u16) * (size_t)2304 * 2304);
  u16*   BTu  = (u16*)alloc(sizeof(u16) * (size_t)1280 * 768);
  u16*   Xhat = (u16*)alloc(sizeof(u16) * (size_t)NEV * 3 * CDIM);
  float* G1   = (float*)alloc(sizeof(float) * (size_t)NEV * MLPH);
  float* G2   = (float*)alloc(sizeof(float) * (size_t)NEV * MLPH);
  float* U    = (float*)alloc(sizeof(float) * (size_t)NEV * MLPH);
  float* V    = (float*)alloc(sizeof(float) * (size_t)NEV * MLPH);
  float* h    = (float*)alloc(sizeof(float) * (size_t)NEV * CDIM);
  float* sv   = (float*)alloc(sizeof(float) * (size_t)NEV * 16);
  float* lpart= (float*)alloc(sizeof(float) * NEV);
  int* deg    = (int*)alloc(sizeof(int) * NEV);
  int* rowp   = (int*)alloc(sizeof(int) * (NEV + 1));
  int* cursor = (int*)alloc(sizeof(int) * NEV);
  int* e_src  = (int*)alloc(sizeof(int) * NEDGE);
  int* e_id   = (int*)alloc(sizeof(int) * NEDGE);
  int* pdeg   = (int*)alloc(sizeof(int) * NEV);
  int* prow   = (int*)alloc(sizeof(int) * (NEV + 1));
  int* pcur   = (int*)alloc(sizeof(int) * NEV);
  int* pidx   = (int*)alloc(sizeof(int) * NPAIR);
  int* mstate = (int*)alloc(sizeof(int) * NPAIR);

  k_zero<<<(NEV + 255) / 256, 256, 0, stream>>>(deg, pdeg, out);
  k_embed<<<NEV, 256, 0, stream>>>(sent, es, st, en, Ahat);
  k_countF<<<NEDGE / 256, 256, 0, stream>>>(pair, deg, pdeg);
  k_scanF<<<1, 256, 0, stream>>>(deg, rowp, cursor, pdeg, prow, pcur);
  k_scatterF<<<NEDGE / 256, 256, 0, stream>>>(pair, rowp, cursor, e_src, e_id,
                                              prow, pcur, pidx);
  cvt_w<<<dim3(72, 32), 256, 0, stream>>>(W1, proj_in_W, proj_W, BTe, BTu);

  // [G1 | G2 | x0] = e_emb @ [W1a | W1b | proj_in_W]  (bf16x3 via K'=3K)
  mgemm<<<dim3(2304 / 128, NEV / 64), 256, 0, stream>>>(
      Ahat, BTe, 3 * EDIM, 0, G1, G2, Xhat, proj_in_b,
      nullptr, nullptr, nullptr, nullptr, nullptr,
      nullptr, nullptr, nullptr, nullptr, nullptr);

  for (int it = 0; it < 3; ++it) {
    mgemm<<<dim3(1280 / 128, NEV / 64), 256, 0, stream>>>(
        Xhat, BTu, 3 * CDIM, 1, G1, G2, nullptr, nullptr,
        b1, proj_b, U, V, h, asi, adi, asj, adj, sv);
    float coef = 1.0f / ((float)(it + 1) * (float)NPAIR);
    k_pred_g<<<NEV, 256, 0, stream>>>(U, V, pair, prow, pidx, W2, b2, target,
                                      mstate, out, lpart, coef);
    k_attn<<<NEV, 256, 0, stream>>>(h, sv, rowp, e_src, e_id, mstate, rel, Xhat,
                                    lpart, out);
  }
  (void)in_sizes; (void)n_in; (void)out_size; (void)ws_size;
}

// Round 8
// 503.803 us; speedup vs baseline: 1.6850x; 1.0803x over previous
//
#include <hip/hip_runtime.h>
#include <cstddef>
#include <cstdint>

#define NEV   4096
#define NPAIR 32768
#define NEDGE (2*NPAIR)
#define EDIM  768
#define CDIM  256
#define MLPH  1024
#define LLEN  256

typedef unsigned short u16;
typedef __attribute__((ext_vector_type(8))) short bhalf8;
typedef __attribute__((ext_vector_type(4))) float f32x4;

// async global->LDS, 16B per lane (HW: wave-uniform LDS base + lane*16)
#define GLOAD_LDS(g, l) __builtin_amdgcn_global_load_lds( \
    (const __attribute__((address_space(1))) unsigned int*)(g), \
    (__attribute__((address_space(3))) unsigned int*)(l), 16, 0, 0)

__device__ inline u16 f2bf(float f) {
  union { float f; unsigned u; } v; v.f = f;
  unsigned r = v.u + 0x7fffu + ((v.u >> 16) & 1u);
  return (u16)(r >> 16);
}
__device__ inline float bf2f(u16 h) {
  union { unsigned u; float f; } v; v.u = ((unsigned)h) << 16; return v.f;
}

// ---------------------------------------------------------------- utilities
__global__ void k_zero(int* __restrict__ deg, int* __restrict__ pdeg,
                       float* __restrict__ out) {
  int i = blockIdx.x * 256 + threadIdx.x;
  if (i < NEV) { deg[i] = 0; pdeg[i] = 0; }
  if (i == 0) out[0] = 0.f;
}

// ---------------------------------------------------------------- e_emb: masked span mean, bf16 hi/lo planes -> Ahat (NEV x 1536)
__global__ void k_embed(const float* __restrict__ sent, const int* __restrict__ es,
                        const int* __restrict__ st, const int* __restrict__ en,
                        u16* __restrict__ Ahat) {
  int node = blockIdx.x;
  int s = es[node];
  int a = st[node];
  int span = en[node] - a;
  float fspan = (float)span;
  const float* base = sent + ((size_t)s * LLEN + a) * EDIM;
  for (int d = threadIdx.x; d < EDIM; d += 256) {
    float acc = 0.f;
    for (int m = 0; m < span; ++m) acc += base[(size_t)m * EDIM + d];
    float e = acc / fspan;
    u16 hi = f2bf(e);
    float lo = e - bf2f(hi);
    size_t b = (size_t)node * (2 * EDIM);
    Ahat[b + d] = hi;
    Ahat[b + EDIM + d] = f2bf(lo);
  }
}

// ---------------------------------------------------------------- fused CSR builds (edge-CSR by dst, pair-CSR by p0)
__global__ void k_countF(const int* __restrict__ pair, int* __restrict__ deg,
                         int* __restrict__ pdeg) {
  int e = blockIdx.x * 256 + threadIdx.x;
  if (e >= NEDGE) return;
  int p = (e < NPAIR) ? e : e - NPAIR;
  int dst = (e < NPAIR) ? pair[2 * p + 1] : pair[2 * p];
  atomicAdd(&deg[dst], 1);
  if (e < NPAIR) atomicAdd(&pdeg[pair[2 * e]], 1);
}

__device__ inline void scan_body(const int* __restrict__ deg, int* __restrict__ rowp,
                                 int* __restrict__ cursor, int* part) {
  int t = threadIdx.x;
  int base = t * 16;
  int sum = 0;
  for (int i = 0; i < 16; ++i) sum += deg[base + i];
  part[t] = sum;
  __syncthreads();
  for (int off = 1; off < 256; off <<= 1) {
    int v = (t >= off) ? part[t - off] : 0;
    __syncthreads();
    part[t] += v;
    __syncthreads();
  }
  int run = (t == 0) ? 0 : part[t - 1];
  for (int i = 0; i < 16; ++i) {
    rowp[base + i] = run;
    cursor[base + i] = 0;
    run += deg[base + i];
  }
  if (t == 255) rowp[NEV] = run;
}

__global__ void k_scanF(const int* __restrict__ deg, int* __restrict__ rowp,
                        int* __restrict__ cursor, const int* __restrict__ pdeg,
                        int* __restrict__ prow, int* __restrict__ pcur) {
  __shared__ int part[256];
  scan_body(deg, rowp, cursor, part);
  __syncthreads();
  scan_body(pdeg, prow, pcur, part);
}

__global__ void k_scatterF(const int* __restrict__ pair, const int* __restrict__ rowp,
                           int* __restrict__ cursor, int* __restrict__ e_src,
                           int* __restrict__ e_id, const int* __restrict__ prow,
                           int* __restrict__ pcur, int* __restrict__ pidx) {
  int e = blockIdx.x * 256 + threadIdx.x;
  if (e >= NEDGE) return;
  int p   = (e < NPAIR) ? e : e - NPAIR;
  int src = (e < NPAIR) ? pair[2 * p]     : pair[2 * p + 1];
  int dst = (e < NPAIR) ? pair[2 * p + 1] : pair[2 * p];
  int pos = rowp[dst] + atomicAdd(&cursor[dst], 1);
  e_src[pos] = src;
  e_id[pos]  = e;
  if (e < NPAIR) {
    int pp = prow[pair[2 * e]] + atomicAdd(&pcur[pair[2 * e]], 1);
    pidx[pp] = e;
  }
}

// ---------------------------------------------------------------- weight conversion: B^T bf16 [hi|lo] planes
// y<24 -> BTe (K=768, N=2304); y>=24 -> BTu (K=256, N=1280, x<40)
__global__ __launch_bounds__(256) void cvt_w(const float* __restrict__ W1,
                                             const float* __restrict__ piW,
                                             const float* __restrict__ projW,
                                             u16* __restrict__ BTe,
                                             u16* __restrict__ BTu)
{
  __shared__ float tile[32][33];
  int which = (blockIdx.y >= 24) ? 1 : 0;
  if (which && blockIdx.x >= 40) return;
  u16* BT = which ? BTu : BTe;
  int K = which ? CDIM : EDIM;
  int ld = K * 2;
  int bk = (which ? (blockIdx.y - 24) : blockIdx.y) * 32;
  int bc = blockIdx.x * 32;
  int tx = threadIdx.x & 31, ty = threadIdx.x >> 5;
#pragma unroll
  for (int rr = 0; rr < 4; ++rr) {
    int k = bk + ty + rr * 8;
    int c = bc + tx;
    float v;
    if (which == 0) {
      v = (c < 1024) ? W1[(size_t)k * MLPH + c]
        : (c < 2048) ? W1[(size_t)(EDIM + k) * MLPH + (c - 1024)]
        : piW[(size_t)k * CDIM + (c - 2048)];
    } else {
      v = (c < 1024) ? W1[(size_t)(2 * EDIM + k) * MLPH + c]
        : projW[(size_t)k * CDIM + (c - 1024)];
    }
    tile[ty + rr * 8][tx] = v;
  }
  __syncthreads();
#pragma unroll
  for (int rr = 0; rr < 4; ++rr) {
    int c = bc + ty + rr * 8;
    int k = bk + tx;
    float v = tile[tx][ty + rr * 8];
    u16 hi = f2bf(v);
    float lo = v - bf2f(hi);
    size_t b = (size_t)c * ld;
    BT[b + k] = hi;
    BT[b + K + k] = f2bf(lo);
  }
}

// ---------------------------------------------------------------- bf16x3 MFMA GEMM, 64x128 tile, hi/lo-plane staging (BK=32/plane)
// A: M x 2K row-major bf16 ([Ah|Al]); BT: N x 2K row-major bf16 (B^T [Bh|Bl])
// 3 MFMA terms per chunk: AhBh + AhBl + AlBh. Grid: (N/128, M/64), no swizzle.
// mode 1 additionally computes attention dots sv from h-region tiles (fused k_s).
__global__ __launch_bounds__(256) void mgemm(
    const u16* __restrict__ A, const u16* __restrict__ BT, int K, int mode,
    float* __restrict__ G1, float* __restrict__ G2, u16* __restrict__ Xhat,
    const float* __restrict__ pib, const float* __restrict__ b1,
    const float* __restrict__ pb, float* __restrict__ U, float* __restrict__ V,
    float* __restrict__ h, const float* __restrict__ asi,
    const float* __restrict__ adi, const float* __restrict__ asj,
    const float* __restrict__ adj, float* __restrict__ sv)
{
  __shared__ u16 Ash[64 * 32];   // 4 KB
  __shared__ u16 Asl[64 * 32];   // 4 KB
  __shared__ u16 Bsh[128 * 32];  // 8 KB
  __shared__ u16 Bsl[128 * 32];  // 8 KB
  int tid = threadIdx.x;
  int wave = tid >> 6, lane = tid & 63;
  int bm = blockIdx.y * 64, bn = blockIdx.x * 128;
  int wm = (wave >> 1) * 32, wn = (wave & 1) * 64;

  int Kp2 = 2 * K;
  int srow = tid >> 2;            // 0..63
  int scol = (tid & 3) << 3;      // 0,8,16,24 (bf16 elems within 32-wide chunk)
  const u16* AgH = A + (size_t)(bm + srow) * Kp2 + scol;
  const u16* BgH = BT + (size_t)(bn + srow) * Kp2 + scol;   // rows bn..bn+63
  const u16* BgH2 = BT + (size_t)(bn + 64 + srow) * Kp2 + scol;

  f32x4 acc[2][4];
#pragma unroll
  for (int i = 0; i < 2; ++i)
#pragma unroll
    for (int j = 0; j < 4; ++j) {
      f32x4 z = {0.f, 0.f, 0.f, 0.f};
      acc[i][j] = z;
    }

  int fr = lane & 15;
  int fq = lane >> 4;

  for (int kc = 0; kc < K; kc += 32) {
    GLOAD_LDS(AgH + kc,       &Ash[tid * 8]);
    GLOAD_LDS(AgH + K + kc,   &Asl[tid * 8]);
    GLOAD_LDS(BgH + kc,       &Bsh[tid * 8]);
    GLOAD_LDS(BgH2 + kc,      &Bsh[2048 + tid * 8]);
    GLOAD_LDS(BgH + K + kc,   &Bsl[tid * 8]);
    GLOAD_LDS(BgH2 + K + kc,  &Bsl[2048 + tid * 8]);
    __syncthreads();
    bhalf8 afh[2], afl[2], bfh[4], bfl[4];
#pragma unroll
    for (int i = 0; i < 2; ++i) {
      afh[i] = *(const bhalf8*)&Ash[(wm + i * 16 + fr) * 32 + fq * 8];
      afl[i] = *(const bhalf8*)&Asl[(wm + i * 16 + fr) * 32 + fq * 8];
    }
#pragma unroll
    for (int j = 0; j < 4; ++j) {
      bfh[j] = *(const bhalf8*)&Bsh[(wn + j * 16 + fr) * 32 + fq * 8];
      bfl[j] = *(const bhalf8*)&Bsl[(wn + j * 16 + fr) * 32 + fq * 8];
    }
#pragma unroll
    for (int i = 0; i < 2; ++i)
#pragma unroll
      for (int j = 0; j < 4; ++j) {
        acc[i][j] = __builtin_amdgcn_mfma_f32_16x16x32_bf16(afh[i], bfh[j], acc[i][j], 0, 0, 0);
        acc[i][j] = __builtin_amdgcn_mfma_f32_16x16x32_bf16(afh[i], bfl[j], acc[i][j], 0, 0, 0);
        acc[i][j] = __builtin_amdgcn_mfma_f32_16x16x32_bf16(afl[i], bfh[j], acc[i][j], 0, 0, 0);
      }
    __syncthreads();
  }

#pragma unroll
  for (int i = 0; i < 2; ++i) {
    int mrow = bm + wm + i * 16 + fq * 4;
#pragma unroll
    for (int g = 0; g < 4; ++g) {
      int m = mrow + g;
#pragma unroll
      for (int j = 0; j < 4; ++j) {
        int c = bn + wn + j * 16 + fr;
        float vv = acc[i][j][g];
        if (mode == 0) {
          if (c < 1024) {
            G1[(size_t)m * MLPH + c] = vv;
          } else if (c < 2048) {
            G2[(size_t)m * MLPH + (c - 1024)] = vv;
          } else {
            int cc = c - 2048;
            float xv = vv + pib[cc];
            u16 hi = f2bf(xv);
            float lo = xv - bf2f(hi);
            size_t b = (size_t)m * (2 * CDIM);
            Xhat[b + cc] = hi;
            Xhat[b + CDIM + cc] = f2bf(lo);
          }
        } else {
          if (c < 1024) {
            size_t idx = (size_t)m * MLPH + c;
            U[idx] = G1[idx] + vv + b1[c];
            V[idx] = G2[idx] - vv;
          } else {
            int cc = c - 1024;
            h[(size_t)m * CDIM + cc] = vv + pb[cc];
          }
        }
      }
    }
  }

  // fused k_s: attention dots from h-region tiles (mode 1, bn >= MLPH)
  if (mode == 1 && bn >= MLPH) {
    int hbase = bn - MLPH + wn;          // head*64 (one head per wave)
    int head = hbase >> 6;
#pragma unroll
    for (int i = 0; i < 2; ++i) {
#pragma unroll
      for (int g = 0; g < 4; ++g) {
        int m = bm + wm + i * 16 + fq * 4 + g;
        float p0 = 0.f, p1 = 0.f, p2 = 0.f, p3 = 0.f;
#pragma unroll
        for (int j = 0; j < 4; ++j) {
          int hc = hbase + j * 16 + fr;  // 0..255 (head*64 + d)
          float hv = acc[i][j][g] + pb[hc];
          p0 += hv * asi[hc];
          p1 += hv * adi[hc];
          p2 += hv * asj[hc];
          p3 += hv * adj[hc];
        }
#pragma unroll
        for (int mm = 1; mm < 16; mm <<= 1) {
          p0 += __shfl_xor(p0, mm);
          p1 += __shfl_xor(p1, mm);
          p2 += __shfl_xor(p2, mm);
          p3 += __shfl_xor(p3, mm);
        }
        if (fr == 0) {
          sv[0 * NEV * 4 + m * 4 + head] = p0;
          sv[1 * NEV * 4 + m * 4 + head] = p1;
          sv[2 * NEV * 4 + m * 4 + head] = p2;
          sv[3 * NEV * 4 + m * 4 + head] = p3;
        }
      }
    }
  }
}

// ---------------------------------------------------------------- pred, p0-grouped: one block per node, U row in LDS, 4 waves over pairs
__global__ __launch_bounds__(256) void k_pred_g(
    const float* __restrict__ U, const float* __restrict__ V,
    const int* __restrict__ pair, const int* __restrict__ prow,
    const int* __restrict__ pidx, const float* __restrict__ W2,
    const float* __restrict__ b2, const int* __restrict__ target,
    int* __restrict__ mstate, float* __restrict__ out,
    float* __restrict__ partials, float lossCoef)
{
  __shared__ float ush[MLPH];
  __shared__ float red[4];
  int n = blockIdx.x;
  int tid = threadIdx.x;
  const float* u = U + (size_t)n * MLPH;
#pragma unroll
  for (int i = 0; i < 4; ++i) ush[tid + i * 256] = u[tid + i * 256];
  __syncthreads();
  int wv = tid >> 6, lane = tid & 63;
  int beg = prow[n], end = prow[n + 1];
  float lsum = 0.f;
  for (int ip = beg + wv; ip < end; ip += 4) {
    int p = pidx[ip];
    int i1 = pair[2 * p + 1];
    const float* v = V + (size_t)i1 * MLPH;
    float a0 = 0.f, a1 = 0.f, a2 = 0.f;
    for (int kb = (lane << 2); kb < MLPH; kb += 256) {
      float4 uu = *(const float4*)(&ush[kb]);
      float4 vv = *(const float4*)(v + kb);
      float h0 = fmaxf(uu.x + vv.x, 0.f);
      float h1 = fmaxf(uu.y + vv.y, 0.f);
      float h2 = fmaxf(uu.z + vv.z, 0.f);
      float h3 = fmaxf(uu.w + vv.w, 0.f);
      const float4* w4 = (const float4*)(W2 + 3 * kb);
      float4 wa = w4[0], wb = w4[1], wc = w4[2];
      a0 += h0 * wa.x + h1 * wa.w + h2 * wb.z + h3 * wc.y;
      a1 += h0 * wa.y + h1 * wb.x + h2 * wb.w + h3 * wc.z;
      a2 += h0 * wa.z + h1 * wb.y + h2 * wc.x + h3 * wc.w;
    }
#pragma unroll
    for (int m = 32; m >= 1; m >>= 1) {
      a0 += __shfl_down(a0, m);
      a1 += __shfl_down(a1, m);
      a2 += __shfl_down(a2, m);
    }
    if (lane == 0) {
      a0 += b2[0]; a1 += b2[1]; a2 += b2[2];
      float mx = fmaxf(a0, fmaxf(a1, a2));
      float e0 = expf(a0 - mx), e1 = expf(a1 - mx), e2 = expf(a2 - mx);
      float sum = e0 + e1 + e2;
      int arg = 0; float best = e0;
      if (e1 > best) { best = e1; arg = 1; }
      if (e2 > best) { best = e2; arg = 2; }
      bool conf = (best / sum) > 0.5f;
      mstate[p] = conf ? arg : -1;
      int t = target[p];
      float predt = (t == 0) ? a0 : ((t == 1) ? a1 : a2);
      float logp = (predt - mx) - logf(sum);
      lsum += -logp * lossCoef;
      float* po = out + 1 + (size_t)p * 3;
      po[0] = a0; po[1] = a1; po[2] = a2;
    }
  }
  if (lane == 0) red[wv] = lsum;
  __syncthreads();
  if (tid == 0) partials[n] = red[0] + red[1] + red[2] + red[3];
}

// ---------------------------------------------------------------- attention aggregate (block per dst node) + fused loss reduction (block 0)
__global__ __launch_bounds__(256) void k_attn(
    const float* __restrict__ h, const float* __restrict__ sv,
    const int* __restrict__ rowp, const int* __restrict__ e_src,
    const int* __restrict__ e_id, const int* __restrict__ mstate,
    const int* __restrict__ rel, u16* __restrict__ Xhat,
    const float* __restrict__ lpart, float* __restrict__ out)
{
  int node = blockIdx.x;
  int t = threadIdx.x;          // dim index 0..255 (head = t>>6)
  int head = t >> 6;
  const float* s_si = sv;
  const float* s_di = sv + NEV * 4;
  const float* s_sj = sv + 2 * NEV * 4;
  const float* s_dj = sv + 3 * NEV * 4;
  float sdi = s_di[node * 4 + head];
  float sdj = s_dj[node * 4 + head];
  int beg = rowp[node], end = rowp[node + 1];
  float aself = s_si[node * 4 + head] + sdi;
  aself = aself > 0.f ? aself : 0.2f * aself;
  float mxi = aself;
  float mxj = -1e9f;
  for (int e = beg; e < end; ++e) {
    int eid = e_id[e];
    int pp = (eid < NPAIR) ? eid : eid - NPAIR;
    int st = mstate[pp];
    bool mall = (eid < NPAIR) ? (st == 1) : (st == 2);
    if (!mall) continue;
    int src = e_src[e];
    if (rel[pp] == 0) {
      float a = s_si[src * 4 + head] + sdi;
      a = a > 0.f ? a : 0.2f * a;
      mxi = fmaxf(mxi, a);
    } else {
      float a = s_sj[src * 4 + head] + sdj;
      a = a > 0.f ? a : 0.2f * a;
      mxj = fmaxf(mxj, a);
    }
  }
  float deni = 0.f, denj = 0.f, acci = 0.f, accj = 0.f;
  {
    float ex = expf(aself - mxi);
    deni += ex;
    acci += ex * h[(size_t)node * CDIM + t];
  }
  for (int e = beg; e < end; ++e) {
    int eid = e_id[e];
    int pp = (eid < NPAIR) ? eid : eid - NPAIR;
    int st = mstate[pp];
    bool mall = (eid < NPAIR) ? (st == 1) : (st == 2);
    if (!mall) continue;
    int src = e_src[e];
    float hval = h[(size_t)src * CDIM + t];
    if (rel[pp] == 0) {
      float a = s_si[src * 4 + head] + sdi;
      a = a > 0.f ? a : 0.2f * a;
      float ex = expf(a - mxi);
      deni += ex; acci += ex * hval;
    } else {
      float a = s_sj[src * 4 + head] + sdj;
      a = a > 0.f ? a : 0.2f * a;
      float ex = expf(a - mxj);
      denj += ex; accj += ex * hval;
    }
  }
  float outv = 0.5f * (acci / (deni + 1e-9f)) + 0.5f * (accj / (denj + 1e-9f));
  u16 hi = f2bf(outv);
  float lo = outv - bf2f(hi);
  size_t b = (size_t)node * (2 * CDIM);
  Xhat[b + t] = hi;
  Xhat[b + CDIM + t] = f2bf(lo);

  // fused loss reduction (one block)
  if (blockIdx.x == 0) {
    __shared__ float sm[256];
    float s = 0.f;
    for (int i = t; i < NEV; i += 256) s += lpart[i];
    sm[t] = s;
    __syncthreads();
    for (int off = 128; off; off >>= 1) {
      if (t < off) sm[t] += sm[t + off];
      __syncthreads();
    }
    if (t == 0) out[0] += sm[0];
  }
}

// ---------------------------------------------------------------- launch
extern "C" void kernel_launch(void* const* d_in, const int* in_sizes, int n_in,
                              void* d_out, int out_size, void* d_ws, size_t ws_size,
                              hipStream_t stream)
{
  const float* sent      = (const float*)d_in[0];
  const float* proj_in_W = (const float*)d_in[1];
  const float* proj_in_b = (const float*)d_in[2];
  const float* proj_W    = (const float*)d_in[3];
  const float* proj_b    = (const float*)d_in[4];
  const float* asi       = (const float*)d_in[5];
  const float* adi       = (const float*)d_in[6];
  const float* asj       = (const float*)d_in[7];
  const float* adj       = (const float*)d_in[8];
  const float* W1        = (const float*)d_in[9];
  const float* b1        = (const float*)d_in[10];
  const float* W2        = (const float*)d_in[11];
  const float* b2        = (const float*)d_in[12];
  const int*   es        = (const int*)d_in[13];
  const int*   st        = (const int*)d_in[14];
  const int*   en        = (const int*)d_in[15];
  const int*   pair      = (const int*)d_in[16];
  const int*   rel       = (const int*)d_in[17];
  const int*   target    = (const int*)d_in[18];
  float* out = (float*)d_out;

  char* w = (char*)d_ws;
  auto alloc = [&](size_t bytes) -> char* {
    char* p = w;
    w += (bytes + 255) & ~(size_t)255;
    return p;
  };
  u16*   Ahat = (u16*)alloc(sizeof(u16) * (size_t)NEV * 2 * EDIM);
  u16*   BTe  = (u16*)alloc(sizeof(u16) * (size_t)2304 * 1536);
  u16*   BTu  = (u16*)alloc(sizeof(u16) * (size_t)1280 * 512);
  u16*   Xhat = (u16*)alloc(sizeof(u16) * (size_t)NEV * 2 * CDIM);
  float* G1   = (float*)alloc(sizeof(float) * (size_t)NEV * MLPH);
  float* G2   = (float*)alloc(sizeof(float) * (size_t)NEV * MLPH);
  float* U    = (float*)alloc(sizeof(float) * (size_t)NEV * MLPH);
  float* V    = (float*)alloc(sizeof(float) * (size_t)NEV * MLPH);
  float* h    = (float*)alloc(sizeof(float) * (size_t)NEV * CDIM);
  float* sv   = (float*)alloc(sizeof(float) * (size_t)NEV * 16);
  float* lpart= (float*)alloc(sizeof(float) * NEV);
  int* deg    = (int*)alloc(sizeof(int) * NEV);
  int* rowp   = (int*)alloc(sizeof(int) * (NEV + 1));
  int* cursor = (int*)alloc(sizeof(int) * NEV);
  int* e_src  = (int*)alloc(sizeof(int) * NEDGE);
  int* e_id   = (int*)alloc(sizeof(int) * NEDGE);
  int* pdeg   = (int*)alloc(sizeof(int) * NEV);
  int* prow   = (int*)alloc(sizeof(int) * (NEV + 1));
  int* pcur   = (int*)alloc(sizeof(int) * NEV);
  int* pidx   = (int*)alloc(sizeof(int) * NPAIR);
  int* mstate = (int*)alloc(sizeof(int) * NPAIR);

  k_zero<<<(NEV + 255) / 256, 256, 0, stream>>>(deg, pdeg, out);
  k_embed<<<NEV, 256, 0, stream>>>(sent, es, st, en, Ahat);
  k_countF<<<NEDGE / 256, 256, 0, stream>>>(pair, deg, pdeg);
  k_scanF<<<1, 256, 0, stream>>>(deg, rowp, cursor, pdeg, prow, pcur);
  k_scatterF<<<NEDGE / 256, 256, 0, stream>>>(pair, rowp, cursor, e_src, e_id,
                                              prow, pcur, pidx);
  cvt_w<<<dim3(72, 32), 256, 0, stream>>>(W1, proj_in_W, proj_W, BTe, BTu);

  // [G1 | G2 | x0] = e_emb @ [W1a | W1b | proj_in_W]  (bf16x3, hi/lo planes)
  mgemm<<<dim3(2304 / 128, NEV / 64), 256, 0, stream>>>(
      Ahat, BTe, EDIM, 0, G1, G2, Xhat, proj_in_b,
      nullptr, nullptr, nullptr, nullptr, nullptr,
      nullptr, nullptr, nullptr, nullptr, nullptr);

  for (int it = 0; it < 3; ++it) {
    mgemm<<<dim3(1280 / 128, NEV / 64), 256, 0, stream>>>(
        Xhat, BTu, CDIM, 1, G1, G2, nullptr, nullptr,
        b1, proj_b, U, V, h, asi, adi, asj, adj, sv);
    float coef = 1.0f / ((float)(it + 1) * (float)NPAIR);
    k_pred_g<<<NEV, 256, 0, stream>>>(U, V, pair, prow, pidx, W2, b2, target,
                                      mstate, out, lpart, coef);
    k_attn<<<NEV, 256, 0, stream>>>(h, sv, rowp, e_src, e_id, mstate, rel, Xhat,
                                    lpart, out);
  }
  (void)in_sizes; (void)n_in; (void)out_size; (void)ws_size;
}

// Round 9
// 483.999 us; speedup vs baseline: 1.7539x; 1.0409x over previous
//
#include <hip/hip_runtime.h>
#include <cstddef>
#include <cstdint>

#define NEV   4096
#define NPAIR 32768
#define NEDGE (2*NPAIR)
#define EDIM  768
#define CDIM  256
#define MLPH  1024
#define LLEN  256

typedef unsigned short u16;
typedef __attribute__((ext_vector_type(8))) short bhalf8;
typedef __attribute__((ext_vector_type(4))) float f32x4;

// async global->LDS, 16B per lane (HW: wave-uniform LDS base + lane*16)
#define GLOAD_LDS(g, l) __builtin_amdgcn_global_load_lds( \
    (const __attribute__((address_space(1))) unsigned int*)(g), \
    (__attribute__((address_space(3))) unsigned int*)(l), 16, 0, 0)

__device__ inline u16 f2bf(float f) {
  union { float f; unsigned u; } v; v.f = f;
  unsigned r = v.u + 0x7fffu + ((v.u >> 16) & 1u);
  return (u16)(r >> 16);
}
__device__ inline float bf2f(u16 h) {
  union { unsigned u; float f; } v; v.u = ((unsigned)h) << 16; return v.f;
}

// ---------------------------------------------------------------- k_prep: embed (blocks 0..4095) | cvt_w (4096..6399) | zero (6400..6415)
__global__ __launch_bounds__(256) void k_prep(
    const float* __restrict__ sent, const int* __restrict__ es,
    const int* __restrict__ st, const int* __restrict__ en,
    u16* __restrict__ Ahat, const float* __restrict__ W1,
    const float* __restrict__ piW, const float* __restrict__ projW,
    u16* __restrict__ BTe, u16* __restrict__ BTu,
    int* __restrict__ deg, int* __restrict__ pdeg, float* __restrict__ out)
{
  __shared__ float tile[32][33];
  int b = blockIdx.x;
  int tid = threadIdx.x;
  if (b < NEV) {
    // ---- embed: masked span mean, bf16 hi/lo planes (float4 loads)
    int node = b;
    int s = es[node];
    int a = st[node];
    int span = en[node] - a;
    float fspan = (float)span;
    const float* base = sent + ((size_t)s * LLEN + a) * EDIM;
    if (tid < 192) {
      int d0 = tid * 4;
      float4 acc = {0.f, 0.f, 0.f, 0.f};
      for (int m = 0; m < span; ++m) {
        float4 v = *(const float4*)(base + (size_t)m * EDIM + d0);
        acc.x += v.x; acc.y += v.y; acc.z += v.z; acc.w += v.w;
      }
      float e[4] = {acc.x / fspan, acc.y / fspan, acc.z / fspan, acc.w / fspan};
      ushort4 hiv, lov;
      u16 h0 = f2bf(e[0]); lov.x = f2bf(e[0] - bf2f(h0)); hiv.x = h0;
      u16 h1 = f2bf(e[1]); lov.y = f2bf(e[1] - bf2f(h1)); hiv.y = h1;
      u16 h2 = f2bf(e[2]); lov.z = f2bf(e[2] - bf2f(h2)); hiv.z = h2;
      u16 h3 = f2bf(e[3]); lov.w = f2bf(e[3] - bf2f(h3)); hiv.w = h3;
      size_t bo = (size_t)node * (2 * EDIM);
      *(ushort4*)&Ahat[bo + d0] = hiv;
      *(ushort4*)&Ahat[bo + EDIM + d0] = lov;
    }
    return;
  }
  if (b < NEV + 2304) {
    // ---- cvt_w: B^T bf16 [hi|lo] planes
    int id = b - NEV;
    int bxx = id % 72, byy = id / 72;       // 72 x 32
    int which = (byy >= 24) ? 1 : 0;
    if (which && bxx >= 40) return;
    u16* BT = which ? BTu : BTe;
    int K = which ? CDIM : EDIM;
    int ld = K * 2;
    int bk = (which ? (byy - 24) : byy) * 32;
    int bc = bxx * 32;
    int tx = tid & 31, ty = tid >> 5;
#pragma unroll
    for (int rr = 0; rr < 4; ++rr) {
      int k = bk + ty + rr * 8;
      int c = bc + tx;
      float v;
      if (which == 0) {
        v = (c < 1024) ? W1[(size_t)k * MLPH + c]
          : (c < 2048) ? W1[(size_t)(EDIM + k) * MLPH + (c - 1024)]
          : piW[(size_t)k * CDIM + (c - 2048)];
      } else {
        v = (c < 1024) ? W1[(size_t)(2 * EDIM + k) * MLPH + c]
          : projW[(size_t)k * CDIM + (c - 1024)];
      }
      tile[ty + rr * 8][tx] = v;
    }
    __syncthreads();
#pragma unroll
    for (int rr = 0; rr < 4; ++rr) {
      int c = bc + ty + rr * 8;
      int k = bk + tx;
      float v = tile[tx][ty + rr * 8];
      u16 hi = f2bf(v);
      float lo = v - bf2f(hi);
      size_t bb = (size_t)c * ld;
      BT[bb + k] = hi;
      BT[bb + K + k] = f2bf(lo);
    }
    return;
  }
  // ---- zero deg/pdeg/out
  int i = (b - NEV - 2304) * 256 + tid;
  if (i < NEV) { deg[i] = 0; pdeg[i] = 0; }
  if (i == 0) out[0] = 0.f;
}

// ---------------------------------------------------------------- fused CSR builds (edge-CSR by dst, pair-CSR by p0)
__global__ void k_countF(const int* __restrict__ pair, int* __restrict__ deg,
                         int* __restrict__ pdeg) {
  int e = blockIdx.x * 256 + threadIdx.x;
  if (e >= NEDGE) return;
  int p = (e < NPAIR) ? e : e - NPAIR;
  int dst = (e < NPAIR) ? pair[2 * p + 1] : pair[2 * p];
  atomicAdd(&deg[dst], 1);
  if (e < NPAIR) atomicAdd(&pdeg[pair[2 * e]], 1);
}

__device__ inline void scan_body(const int* __restrict__ deg, int* __restrict__ rowp,
                                 int* __restrict__ cursor, int* part) {
  int t = threadIdx.x;
  int base = t * 16;
  int sum = 0;
  for (int i = 0; i < 16; ++i) sum += deg[base + i];
  part[t] = sum;
  __syncthreads();
  for (int off = 1; off < 256; off <<= 1) {
    int v = (t >= off) ? part[t - off] : 0;
    __syncthreads();
    part[t] += v;
    __syncthreads();
  }
  int run = (t == 0) ? 0 : part[t - 1];
  for (int i = 0; i < 16; ++i) {
    rowp[base + i] = run;
    cursor[base + i] = 0;
    run += deg[base + i];
  }
  if (t == 255) rowp[NEV] = run;
}

__global__ void k_scanF(const int* __restrict__ deg, int* __restrict__ rowp,
                        int* __restrict__ cursor, const int* __restrict__ pdeg,
                        int* __restrict__ prow, int* __restrict__ pcur) {
  __shared__ int part[256];
  scan_body(deg, rowp, cursor, part);
  __syncthreads();
  scan_body(pdeg, prow, pcur, part);
}

__global__ void k_scatterF(const int* __restrict__ pair, const int* __restrict__ rowp,
                           int* __restrict__ cursor, int* __restrict__ e_src,
                           int* __restrict__ e_id, const int* __restrict__ prow,
                           int* __restrict__ pcur, int* __restrict__ pidx) {
  int e = blockIdx.x * 256 + threadIdx.x;
  if (e >= NEDGE) return;
  int p   = (e < NPAIR) ? e : e - NPAIR;
  int src = (e < NPAIR) ? pair[2 * p]     : pair[2 * p + 1];
  int dst = (e < NPAIR) ? pair[2 * p + 1] : pair[2 * p];
  int pos = rowp[dst] + atomicAdd(&cursor[dst], 1);
  e_src[pos] = src;
  e_id[pos]  = e;
  if (e < NPAIR) {
    int pp = prow[pair[2 * e]] + atomicAdd(&pcur[pair[2 * e]], 1);
    pidx[pp] = e;
  }
}

// ---------------------------------------------------------------- bf16x3 MFMA GEMM, 64x128 tile, hi/lo planes, 2-phase double-buffer
// A: M x 2K ([Ah|Al]); BT: N x 2K (B^T [Bh|Bl]). Grid: (N/128, M/64).
// K-loop: stage(next, buf^1) BEFORE compute(buf); one __syncthreads per chunk
// (its implicit vmcnt(0) is the drain point) -> loads overlap MFMA.
__global__ __launch_bounds__(256) void mgemm(
    const u16* __restrict__ A, const u16* __restrict__ BT, int K, int mode,
    float* __restrict__ G1, float* __restrict__ G2, u16* __restrict__ Xhat,
    const float* __restrict__ pib, const float* __restrict__ b1,
    const float* __restrict__ pb, float* __restrict__ U, float* __restrict__ V,
    float* __restrict__ h, const float* __restrict__ asi,
    const float* __restrict__ adi, const float* __restrict__ asj,
    const float* __restrict__ adj, float* __restrict__ sv)
{
  __shared__ u16 Ash[2 * 64 * 32];   //  8 KB
  __shared__ u16 Asl[2 * 64 * 32];   //  8 KB
  __shared__ u16 Bsh[2 * 128 * 32];  // 16 KB
  __shared__ u16 Bsl[2 * 128 * 32];  // 16 KB
  int tid = threadIdx.x;
  int wave = tid >> 6, lane = tid & 63;
  int bm = blockIdx.y * 64, bn = blockIdx.x * 128;
  int wm = (wave >> 1) * 32, wn = (wave & 1) * 64;

  int Kp2 = 2 * K;
  int srow = tid >> 2;            // 0..63
  int scol = (tid & 3) << 3;      // 0,8,16,24
  const u16* AgH  = A + (size_t)(bm + srow) * Kp2 + scol;
  const u16* BgH  = BT + (size_t)(bn + srow) * Kp2 + scol;
  const u16* BgH2 = BT + (size_t)(bn + 64 + srow) * Kp2 + scol;

  auto STAGE = [&](int buf, int kc) {
    u16* as = Ash + buf * 2048;
    u16* al = Asl + buf * 2048;
    u16* bs = Bsh + buf * 4096;
    u16* bl = Bsl + buf * 4096;
    GLOAD_LDS(AgH + kc,       &as[tid * 8]);
    GLOAD_LDS(AgH + K + kc,   &al[tid * 8]);
    GLOAD_LDS(BgH + kc,       &bs[tid * 8]);
    GLOAD_LDS(BgH2 + kc,      &bs[2048 + tid * 8]);
    GLOAD_LDS(BgH + K + kc,   &bl[tid * 8]);
    GLOAD_LDS(BgH2 + K + kc,  &bl[2048 + tid * 8]);
  };

  f32x4 acc[2][4];
#pragma unroll
  for (int i = 0; i < 2; ++i)
#pragma unroll
    for (int j = 0; j < 4; ++j) {
      f32x4 z = {0.f, 0.f, 0.f, 0.f};
      acc[i][j] = z;
    }

  int fr = lane & 15;
  int fq = lane >> 4;

  STAGE(0, 0);
  __syncthreads();
  int cur = 0;
  for (int kc = 0; kc < K; kc += 32) {
    if (kc + 32 < K) STAGE(cur ^ 1, kc + 32);
    const u16* as = Ash + cur * 2048;
    const u16* al = Asl + cur * 2048;
    const u16* bs = Bsh + cur * 4096;
    const u16* bl = Bsl + cur * 4096;
    bhalf8 afh[2], afl[2], bfh[4], bfl[4];
#pragma unroll
    for (int i = 0; i < 2; ++i) {
      afh[i] = *(const bhalf8*)&as[(wm + i * 16 + fr) * 32 + fq * 8];
      afl[i] = *(const bhalf8*)&al[(wm + i * 16 + fr) * 32 + fq * 8];
    }
#pragma unroll
    for (int j = 0; j < 4; ++j) {
      bfh[j] = *(const bhalf8*)&bs[(wn + j * 16 + fr) * 32 + fq * 8];
      bfl[j] = *(const bhalf8*)&bl[(wn + j * 16 + fr) * 32 + fq * 8];
    }
#pragma unroll
    for (int i = 0; i < 2; ++i)
#pragma unroll
      for (int j = 0; j < 4; ++j) {
        acc[i][j] = __builtin_amdgcn_mfma_f32_16x16x32_bf16(afh[i], bfh[j], acc[i][j], 0, 0, 0);
        acc[i][j] = __builtin_amdgcn_mfma_f32_16x16x32_bf16(afh[i], bfl[j], acc[i][j], 0, 0, 0);
        acc[i][j] = __builtin_amdgcn_mfma_f32_16x16x32_bf16(afl[i], bfh[j], acc[i][j], 0, 0, 0);
      }
    __syncthreads();
    cur ^= 1;
  }

#pragma unroll
  for (int i = 0; i < 2; ++i) {
    int mrow = bm + wm + i * 16 + fq * 4;
#pragma unroll
    for (int g = 0; g < 4; ++g) {
      int m = mrow + g;
#pragma unroll
      for (int j = 0; j < 4; ++j) {
        int c = bn + wn + j * 16 + fr;
        float vv = acc[i][j][g];
        if (mode == 0) {
          if (c < 1024) {
            G1[(size_t)m * MLPH + c] = vv;
          } else if (c < 2048) {
            G2[(size_t)m * MLPH + (c - 1024)] = vv;
          } else {
            int cc = c - 2048;
            float xv = vv + pib[cc];
            u16 hi = f2bf(xv);
            float lo = xv - bf2f(hi);
            size_t b = (size_t)m * (2 * CDIM);
            Xhat[b + cc] = hi;
            Xhat[b + CDIM + cc] = f2bf(lo);
          }
        } else {
          if (c < 1024) {
            size_t idx = (size_t)m * MLPH + c;
            U[idx] = G1[idx] + vv + b1[c];
            V[idx] = G2[idx] - vv;
          } else {
            int cc = c - 1024;
            h[(size_t)m * CDIM + cc] = vv + pb[cc];
          }
        }
      }
    }
  }

  // fused k_s: attention dots from h-region tiles (mode 1, bn >= MLPH)
  if (mode == 1 && bn >= MLPH) {
    int hbase = bn - MLPH + wn;          // head*64 (one head per wave)
    int head = hbase >> 6;
#pragma unroll
    for (int i = 0; i < 2; ++i) {
#pragma unroll
      for (int g = 0; g < 4; ++g) {
        int m = bm + wm + i * 16 + fq * 4 + g;
        float p0 = 0.f, p1 = 0.f, p2 = 0.f, p3 = 0.f;
#pragma unroll
        for (int j = 0; j < 4; ++j) {
          int hc = hbase + j * 16 + fr;  // 0..255 (head*64 + d)
          float hv = acc[i][j][g] + pb[hc];
          p0 += hv * asi[hc];
          p1 += hv * adi[hc];
          p2 += hv * asj[hc];
          p3 += hv * adj[hc];
        }
#pragma unroll
        for (int mm = 1; mm < 16; mm <<= 1) {
          p0 += __shfl_xor(p0, mm);
          p1 += __shfl_xor(p1, mm);
          p2 += __shfl_xor(p2, mm);
          p3 += __shfl_xor(p3, mm);
        }
        if (fr == 0) {
          sv[0 * NEV * 4 + m * 4 + head] = p0;
          sv[1 * NEV * 4 + m * 4 + head] = p1;
          sv[2 * NEV * 4 + m * 4 + head] = p2;
          sv[3 * NEV * 4 + m * 4 + head] = p3;
        }
      }
    }
  }
}

// ---------------------------------------------------------------- pred, p0-grouped: one block per node, U row in LDS, 4 waves over pairs
__global__ __launch_bounds__(256) void k_pred_g(
    const float* __restrict__ U, const float* __restrict__ V,
    const int* __restrict__ pair, const int* __restrict__ prow,
    const int* __restrict__ pidx, const float* __restrict__ W2,
    const float* __restrict__ b2, const int* __restrict__ target,
    int* __restrict__ mstate, float* __restrict__ out,
    float* __restrict__ partials, float lossCoef)
{
  __shared__ float ush[MLPH];
  __shared__ float red[4];
  int n = blockIdx.x;
  int tid = threadIdx.x;
  const float* u = U + (size_t)n * MLPH;
#pragma unroll
  for (int i = 0; i < 4; ++i) ush[tid + i * 256] = u[tid + i * 256];
  __syncthreads();
  int wv = tid >> 6, lane = tid & 63;
  int beg = prow[n], end = prow[n + 1];
  float lsum = 0.f;
  for (int ip = beg + wv; ip < end; ip += 4) {
    int p = pidx[ip];
    int i1 = pair[2 * p + 1];
    const float* v = V + (size_t)i1 * MLPH;
    float a0 = 0.f, a1 = 0.f, a2 = 0.f;
    for (int kb = (lane << 2); kb < MLPH; kb += 256) {
      float4 uu = *(const float4*)(&ush[kb]);
      float4 vv = *(const float4*)(v + kb);
      float h0 = fmaxf(uu.x + vv.x, 0.f);
      float h1 = fmaxf(uu.y + vv.y, 0.f);
      float h2 = fmaxf(uu.z + vv.z, 0.f);
      float h3 = fmaxf(uu.w + vv.w, 0.f);
      const float4* w4 = (const float4*)(W2 + 3 * kb);
      float4 wa = w4[0], wb = w4[1], wc = w4[2];
      a0 += h0 * wa.x + h1 * wa.w + h2 * wb.z + h3 * wc.y;
      a1 += h0 * wa.y + h1 * wb.x + h2 * wb.w + h3 * wc.z;
      a2 += h0 * wa.z + h1 * wb.y + h2 * wc.x + h3 * wc.w;
    }
#pragma unroll
    for (int m = 32; m >= 1; m >>= 1) {
      a0 += __shfl_down(a0, m);
      a1 += __shfl_down(a1, m);
      a2 += __shfl_down(a2, m);
    }
    if (lane == 0) {
      a0 += b2[0]; a1 += b2[1]; a2 += b2[2];
      float mx = fmaxf(a0, fmaxf(a1, a2));
      float e0 = expf(a0 - mx), e1 = expf(a1 - mx), e2 = expf(a2 - mx);
      float sum = e0 + e1 + e2;
      int arg = 0; float best = e0;
      if (e1 > best) { best = e1; arg = 1; }
      if (e2 > best) { best = e2; arg = 2; }
      bool conf = (best / sum) > 0.5f;
      mstate[p] = conf ? arg : -1;
      int t = target[p];
      float predt = (t == 0) ? a0 : ((t == 1) ? a1 : a2);
      float logp = (predt - mx) - logf(sum);
      lsum += -logp * lossCoef;
      float* po = out + 1 + (size_t)p * 3;
      po[0] = a0; po[1] = a1; po[2] = a2;
    }
  }
  if (lane == 0) red[wv] = lsum;
  __syncthreads();
  if (tid == 0) partials[n] = red[0] + red[1] + red[2] + red[3];
}

// ---------------------------------------------------------------- attention aggregate (block per dst node) + fused loss reduction (block 0)
__global__ __launch_bounds__(256) void k_attn(
    const float* __restrict__ h, const float* __restrict__ sv,
    const int* __restrict__ rowp, const int* __restrict__ e_src,
    const int* __restrict__ e_id, const int* __restrict__ mstate,
    const int* __restrict__ rel, u16* __restrict__ Xhat,
    const float* __restrict__ lpart, float* __restrict__ out)
{
  int node = blockIdx.x;
  int t = threadIdx.x;          // dim index 0..255 (head = t>>6)
  int head = t >> 6;
  const float* s_si = sv;
  const float* s_di = sv + NEV * 4;
  const float* s_sj = sv + 2 * NEV * 4;
  const float* s_dj = sv + 3 * NEV * 4;
  float sdi = s_di[node * 4 + head];
  float sdj = s_dj[node * 4 + head];
  int beg = rowp[node], end = rowp[node + 1];
  float aself = s_si[node * 4 + head] + sdi;
  aself = aself > 0.f ? aself : 0.2f * aself;
  float mxi = aself;
  float mxj = -1e9f;
  for (int e = beg; e < end; ++e) {
    int eid = e_id[e];
    int pp = (eid < NPAIR) ? eid : eid - NPAIR;
    int st = mstate[pp];
    bool mall = (eid < NPAIR) ? (st == 1) : (st == 2);
    if (!mall) continue;
    int src = e_src[e];
    if (rel[pp] == 0) {
      float a = s_si[src * 4 + head] + sdi;
      a = a > 0.f ? a : 0.2f * a;
      mxi = fmaxf(mxi, a);
    } else {
      float a = s_sj[src * 4 + head] + sdj;
      a = a > 0.f ? a : 0.2f * a;
      mxj = fmaxf(mxj, a);
    }
  }
  float deni = 0.f, denj = 0.f, acci = 0.f, accj = 0.f;
  {
    float ex = expf(aself - mxi);
    deni += ex;
    acci += ex * h[(size_t)node * CDIM + t];
  }
  for (int e = beg; e < end; ++e) {
    int eid = e_id[e];
    int pp = (eid < NPAIR) ? eid : eid - NPAIR;
    int st = mstate[pp];
    bool mall = (eid < NPAIR) ? (st == 1) : (st == 2);
    if (!mall) continue;
    int src = e_src[e];
    float hval = h[(size_t)src * CDIM + t];
    if (rel[pp] == 0) {
      float a = s_si[src * 4 + head] + sdi;
      a = a > 0.f ? a : 0.2f * a;
      float ex = expf(a - mxi);
      deni += ex; acci += ex * hval;
    } else {
      float a = s_sj[src * 4 + head] + sdj;
      a = a > 0.f ? a : 0.2f * a;
      float ex = expf(a - mxj);
      denj += ex; accj += ex * hval;
    }
  }
  float outv = 0.5f * (acci / (deni + 1e-9f)) + 0.5f * (accj / (denj + 1e-9f));
  u16 hi = f2bf(outv);
  float lo = outv - bf2f(hi);
  size_t b = (size_t)node * (2 * CDIM);
  Xhat[b + t] = hi;
  Xhat[b + CDIM + t] = f2bf(lo);

  // fused loss reduction (one block)
  if (blockIdx.x == 0) {
    __shared__ float sm[256];
    float s = 0.f;
    for (int i = t; i < NEV; i += 256) s += lpart[i];
    sm[t] = s;
    __syncthreads();
    for (int off = 128; off; off >>= 1) {
      if (t < off) sm[t] += sm[t + off];
      __syncthreads();
    }
    if (t == 0) out[0] += sm[0];
  }
}

// ---------------------------------------------------------------- launch
extern "C" void kernel_launch(void* const* d_in, const int* in_sizes, int n_in,
                              void* d_out, int out_size, void* d_ws, size_t ws_size,
                              hipStream_t stream)
{
  const float* sent      = (const float*)d_in[0];
  const float* proj_in_W = (const float*)d_in[1];
  const float* proj_in_b = (const float*)d_in[2];
  const float* proj_W    = (const float*)d_in[3];
  const float* proj_b    = (const float*)d_in[4];
  const float* asi       = (const float*)d_in[5];
  const float* adi       = (const float*)d_in[6];
  const float* asj       = (const float*)d_in[7];
  const float* adj       = (const float*)d_in[8];
  const float* W1        = (const float*)d_in[9];
  const float* b1        = (const float*)d_in[10];
  const float* W2        = (const float*)d_in[11];
  const float* b2        = (const float*)d_in[12];
  const int*   es        = (const int*)d_in[13];
  const int*   st        = (const int*)d_in[14];
  const int*   en        = (const int*)d_in[15];
  const int*   pair      = (const int*)d_in[16];
  const int*   rel       = (const int*)d_in[17];
  const int*   target    = (const int*)d_in[18];
  float* out = (float*)d_out;

  char* w = (char*)d_ws;
  auto alloc = [&](size_t bytes) -> char* {
    char* p = w;
    w += (bytes + 255) & ~(size_t)255;
    return p;
  };
  u16*   Ahat = (u16*)alloc(sizeof(u16) * (size_t)NEV * 2 * EDIM);
  u16*   BTe  = (u16*)alloc(sizeof(u16) * (size_t)2304 * 1536);
  u16*   BTu  = (u16*)alloc(sizeof(u16) * (size_t)1280 * 512);
  u16*   Xhat = (u16*)alloc(sizeof(u16) * (size_t)NEV * 2 * CDIM);
  float* G1   = (float*)alloc(sizeof(float) * (size_t)NEV * MLPH);
  float* G2   = (float*)alloc(sizeof(float) * (size_t)NEV * MLPH);
  float* U    = (float*)alloc(sizeof(float) * (size_t)NEV * MLPH);
  float* V    = (float*)alloc(sizeof(float) * (size_t)NEV * MLPH);
  float* h    = (float*)alloc(sizeof(float) * (size_t)NEV * CDIM);
  float* sv   = (float*)alloc(sizeof(float) * (size_t)NEV * 16);
  float* lpart= (float*)alloc(sizeof(float) * NEV);
  int* deg    = (int*)alloc(sizeof(int) * NEV);
  int* rowp   = (int*)alloc(sizeof(int) * (NEV + 1));
  int* cursor = (int*)alloc(sizeof(int) * NEV);
  int* e_src  = (int*)alloc(sizeof(int) * NEDGE);
  int* e_id   = (int*)alloc(sizeof(int) * NEDGE);
  int* pdeg   = (int*)alloc(sizeof(int) * NEV);
  int* prow   = (int*)alloc(sizeof(int) * (NEV + 1));
  int* pcur   = (int*)alloc(sizeof(int) * NEV);
  int* pidx   = (int*)alloc(sizeof(int) * NPAIR);
  int* mstate = (int*)alloc(sizeof(int) * NPAIR);

  k_prep<<<NEV + 2304 + 16, 256, 0, stream>>>(sent, es, st, en, Ahat,
                                              W1, proj_in_W, proj_W, BTe, BTu,
                                              deg, pdeg, out);
  k_countF<<<NEDGE / 256, 256, 0, stream>>>(pair, deg, pdeg);
  k_scanF<<<1, 256, 0, stream>>>(deg, rowp, cursor, pdeg, prow, pcur);
  k_scatterF<<<NEDGE / 256, 256, 0, stream>>>(pair, rowp, cursor, e_src, e_id,
                                              prow, pcur, pidx);

  // [G1 | G2 | x0] = e_emb @ [W1a | W1b | proj_in_W]  (bf16x3, hi/lo planes)
  mgemm<<<dim3(2304 / 128, NEV / 64), 256, 0, stream>>>(
      Ahat, BTe, EDIM, 0, G1, G2, Xhat, proj_in_b,
      nullptr, nullptr, nullptr, nullptr, nullptr,
      nullptr, nullptr, nullptr, nullptr, nullptr);

  for (int it = 0; it < 3; ++it) {
    mgemm<<<dim3(1280 / 128, NEV / 64), 256, 0, stream>>>(
        Xhat, BTu, CDIM, 1, G1, G2, nullptr, nullptr,
        b1, proj_b, U, V, h, asi, adi, asj, adj, sv);
    float coef = 1.0f / ((float)(it + 1) * (float)NPAIR);
    k_pred_g<<<NEV, 256, 0, stream>>>(U, V, pair, prow, pidx, W2, b2, target,
                                      mstate, out, lpart, coef);
    k_attn<<<NEV, 256, 0, stream>>>(h, sv, rowp, e_src, e_id, mstate, rel, Xhat,
                                    lpart, out);
  }
  (void)in_sizes; (void)n_in; (void)out_size; (void)ws_size;
}